// Round 7
// baseline (4029.437 us; speedup 1.0000x reference)
//
#include <hip/hip_runtime.h>
#include <hip/hip_bf16.h>
#include <math.h>

// Model dims
#define BB     16
#define LL     197
#define DD     384
#define DEPTH  24
#define DI     768
#define DSN    16
#define DTR    24
#define NC     1000
#define TT     (BB*LL)      // 3152 tokens
#define NPATCH 196
#define EPSV   1e-5f

// chunked scan config: 12 chunks of 17 tokens (11*17=187, last=10)
#define NCHUNK 12
#define CH     17

typedef __attribute__((ext_vector_type(8))) short short8;
typedef __attribute__((ext_vector_type(4))) float f32x4;

__device__ __forceinline__ short f2bf(float f) {
  union { float f; unsigned u; } v; v.f = f;
  unsigned u = v.u + 0x7fffu + ((v.u >> 16) & 1u);
  return (short)(u >> 16);
}

// ---------------------------------------------------------------------------
// init: zero res, write cls token row of hid
// ---------------------------------------------------------------------------
__global__ __launch_bounds__(256) void k_init(const float* __restrict__ cls,
                                              const float* __restrict__ pos,
                                              float* __restrict__ res,
                                              float* __restrict__ hid) {
  int i = blockIdx.x * 256 + threadIdx.x;
  if (i < TT * DD) res[i] = 0.f;
  if (i < BB * DD) {
    int b = i / DD, d = i % DD;
    hid[(size_t)(b * LL) * DD + d] = cls[d] + pos[d];
  }
}

// ---------------------------------------------------------------------------
// patch embed: bf16 MFMA GEMM with fused im2col.
// ---------------------------------------------------------------------------
__global__ __launch_bounds__(256) void k_patch(const float* __restrict__ x,
                                               const float* __restrict__ pw,
                                               const float* __restrict__ pb,
                                               const float* __restrict__ pos,
                                               float* __restrict__ hid) {
  __shared__ short sA[64 * 40];
  __shared__ short sB[64 * 40];
  const int tid = threadIdx.x;
  const int m0 = blockIdx.x * 64, n0 = blockIdx.y * 64;
  const int srow = tid >> 2;
  const int skq = (tid & 3) * 8;
  const int lane = tid & 63, w = tid >> 6;
  const int wm = (w >> 1) * 32, wn = (w & 1) * 32;
  const int fr = lane & 15;
  const int fk = (lane >> 4) * 8;
  f32x4 acc[2][2] = {};
  const int m = m0 + srow;
  const int b = m / NPATCH;
  const int p = m % NPATCH;
  const int ph = p / 14, pwi = p % 14;
  const float* Wrow = pw + (size_t)(n0 + srow) * 768 + skq;
  for (int k0 = 0; k0 < 768; k0 += 32) {
    int k = k0 + skq;
    int c = k >> 8, rr = (k >> 4) & 15, kw = k & 15;
    const float* xrow = &x[(size_t)(((b * 3 + c) * 224) + (ph * 16 + rr)) * 224 +
                           (pwi * 16 + kw)];
    float4 a0 = *(const float4*)&xrow[0];
    float4 a1 = *(const float4*)&xrow[4];
    float4 b0 = *(const float4*)&Wrow[k0];
    float4 b1 = *(const float4*)&Wrow[k0 + 4];
    short8 av = {f2bf(a0.x), f2bf(a0.y), f2bf(a0.z), f2bf(a0.w),
                 f2bf(a1.x), f2bf(a1.y), f2bf(a1.z), f2bf(a1.w)};
    short8 bv = {f2bf(b0.x), f2bf(b0.y), f2bf(b0.z), f2bf(b0.w),
                 f2bf(b1.x), f2bf(b1.y), f2bf(b1.z), f2bf(b1.w)};
    *(short8*)&sA[srow * 40 + skq] = av;
    *(short8*)&sB[srow * 40 + skq] = bv;
    __syncthreads();
    short8 af0 = *(const short8*)&sA[(wm + fr) * 40 + fk];
    short8 af1 = *(const short8*)&sA[(wm + 16 + fr) * 40 + fk];
    short8 bf0 = *(const short8*)&sB[(wn + fr) * 40 + fk];
    short8 bf1 = *(const short8*)&sB[(wn + 16 + fr) * 40 + fk];
    acc[0][0] = __builtin_amdgcn_mfma_f32_16x16x32_bf16(af0, bf0, acc[0][0], 0, 0, 0);
    acc[0][1] = __builtin_amdgcn_mfma_f32_16x16x32_bf16(af0, bf1, acc[0][1], 0, 0, 0);
    acc[1][0] = __builtin_amdgcn_mfma_f32_16x16x32_bf16(af1, bf0, acc[1][0], 0, 0, 0);
    acc[1][1] = __builtin_amdgcn_mfma_f32_16x16x32_bf16(af1, bf1, acc[1][1], 0, 0, 0);
    __syncthreads();
  }
#pragma unroll
  for (int i = 0; i < 2; i++)
#pragma unroll
    for (int j = 0; j < 2; j++)
#pragma unroll
      for (int q = 0; q < 4; q++) {
        int mm = m0 + wm + i * 16 + (lane >> 4) * 4 + q;
        int nn = n0 + wn + j * 16 + (lane & 15);
        int b2 = mm / NPATCH, pp = mm % NPATCH;
        int tok = b2 * LL + 1 + pp;
        hid[(size_t)tok * DD + nn] = acc[i][j][q] + pb[nn] + pos[(size_t)(1 + pp) * DD + nn];
      }
}

// ---------------------------------------------------------------------------
// bf16 MFMA GEMM: C[M,N] = A[M,K] * W[N,K]^T  (used for in_proj)
// ---------------------------------------------------------------------------
__global__ __launch_bounds__(256) void k_gemm_mfma(const float* __restrict__ A, int lda,
                                                   const float* __restrict__ W, int ldb,
                                                   float* __restrict__ C, int ldc,
                                                   int M, int N, int K) {
  __shared__ short sA[64 * 40];
  __shared__ short sB[64 * 40];
  const int tid = threadIdx.x;
  const int m0 = blockIdx.x * 64, n0 = blockIdx.y * 64;
  const int srow = tid >> 2;
  const int skq = (tid & 3) * 8;
  const int lane = tid & 63, w = tid >> 6;
  const int wm = (w >> 1) * 32, wn = (w & 1) * 32;
  const int fr = lane & 15;
  const int fk = (lane >> 4) * 8;
  f32x4 acc[2][2] = {};
  const int am = m0 + srow;
  const bool aok = am < M;
  const float* Arow = A + (size_t)am * lda + skq;
  const float* Wrow = W + (size_t)(n0 + srow) * ldb + skq;
  for (int k0 = 0; k0 < K; k0 += 32) {
    float4 a0 = {0, 0, 0, 0}, a1 = {0, 0, 0, 0};
    if (aok) {
      a0 = *(const float4*)&Arow[k0];
      a1 = *(const float4*)&Arow[k0 + 4];
    }
    float4 b0 = *(const float4*)&Wrow[k0];
    float4 b1 = *(const float4*)&Wrow[k0 + 4];
    short8 av = {f2bf(a0.x), f2bf(a0.y), f2bf(a0.z), f2bf(a0.w),
                 f2bf(a1.x), f2bf(a1.y), f2bf(a1.z), f2bf(a1.w)};
    short8 bv = {f2bf(b0.x), f2bf(b0.y), f2bf(b0.z), f2bf(b0.w),
                 f2bf(b1.x), f2bf(b1.y), f2bf(b1.z), f2bf(b1.w)};
    *(short8*)&sA[srow * 40 + skq] = av;
    *(short8*)&sB[srow * 40 + skq] = bv;
    __syncthreads();
    short8 af0 = *(const short8*)&sA[(wm + fr) * 40 + fk];
    short8 af1 = *(const short8*)&sA[(wm + 16 + fr) * 40 + fk];
    short8 bf0 = *(const short8*)&sB[(wn + fr) * 40 + fk];
    short8 bf1 = *(const short8*)&sB[(wn + 16 + fr) * 40 + fk];
    acc[0][0] = __builtin_amdgcn_mfma_f32_16x16x32_bf16(af0, bf0, acc[0][0], 0, 0, 0);
    acc[0][1] = __builtin_amdgcn_mfma_f32_16x16x32_bf16(af0, bf1, acc[0][1], 0, 0, 0);
    acc[1][0] = __builtin_amdgcn_mfma_f32_16x16x32_bf16(af1, bf0, acc[1][0], 0, 0, 0);
    acc[1][1] = __builtin_amdgcn_mfma_f32_16x16x32_bf16(af1, bf1, acc[1][1], 0, 0, 0);
    __syncthreads();
  }
#pragma unroll
  for (int i = 0; i < 2; i++)
#pragma unroll
    for (int j = 0; j < 2; j++)
#pragma unroll
      for (int q = 0; q < 4; q++) {
        int mm = m0 + wm + i * 16 + (lane >> 4) * 4 + q;
        int nn = n0 + wn + j * 16 + (lane & 15);
        if (mm < M) C[(size_t)mm * ldc + nn] = acc[i][j][q];
      }
}

// ---------------------------------------------------------------------------
// x_proj: bf16 MFMA, BM=16, N=56 padded to 64, K=768
// ---------------------------------------------------------------------------
__global__ __launch_bounds__(256) void k_xproj(const float* __restrict__ A,
                                               const float* __restrict__ W,
                                               float* __restrict__ C) {
  __shared__ short sA[16 * 40];
  __shared__ short sB[64 * 40];
  const int tid = threadIdx.x;
  const int m0 = blockIdx.x * 16;
  const int lane = tid & 63, w = tid >> 6;
  const int wn = w * 16;
  const int fr = lane & 15;
  const int fk = (lane >> 4) * 8;
  const int srow = tid >> 2;
  const int skq = (tid & 3) * 8;
  f32x4 acc = {};
  for (int k0 = 0; k0 < DI; k0 += 32) {
    if (tid < 64) {
      float4 a0 = *(const float4*)&A[(size_t)(m0 + srow) * DI + k0 + skq];
      float4 a1 = *(const float4*)&A[(size_t)(m0 + srow) * DI + k0 + skq + 4];
      short8 av = {f2bf(a0.x), f2bf(a0.y), f2bf(a0.z), f2bf(a0.w),
                   f2bf(a1.x), f2bf(a1.y), f2bf(a1.z), f2bf(a1.w)};
      *(short8*)&sA[srow * 40 + skq] = av;
    }
    short8 bv = {0, 0, 0, 0, 0, 0, 0, 0};
    if (srow < 56) {
      float4 b0 = *(const float4*)&W[(size_t)srow * DI + k0 + skq];
      float4 b1 = *(const float4*)&W[(size_t)srow * DI + k0 + skq + 4];
      bv = short8{f2bf(b0.x), f2bf(b0.y), f2bf(b0.z), f2bf(b0.w),
                  f2bf(b1.x), f2bf(b1.y), f2bf(b1.z), f2bf(b1.w)};
    }
    *(short8*)&sB[srow * 40 + skq] = bv;
    __syncthreads();
    short8 af = *(const short8*)&sA[fr * 40 + fk];
    short8 bf = *(const short8*)&sB[(wn + fr) * 40 + fk];
    acc = __builtin_amdgcn_mfma_f32_16x16x32_bf16(af, bf, acc, 0, 0, 0);
    __syncthreads();
  }
#pragma unroll
  for (int q = 0; q < 4; q++) {
    int mm = m0 + (lane >> 4) * 4 + q;
    int nn = wn + (lane & 15);
    if (nn < 56) C[(size_t)mm * 56 + nn] = acc[q];
  }
}

// ---------------------------------------------------------------------------
// out_proj + residual + LN fused: hid_tile = Y @ Wout^T (BM=16, BN=384 full
// row); res += hid_tile; u = LN(res)*nw+nb (next layer's norm). 197 blocks.
// ---------------------------------------------------------------------------
__global__ __launch_bounds__(256) void k_oproj(const float* __restrict__ Y,
                                               const float* __restrict__ W,
                                               float* __restrict__ res,
                                               float* __restrict__ u,
                                               const float* __restrict__ nw,
                                               const float* __restrict__ nb) {
  __shared__ short sA[16 * 40];
  __shared__ short sB[DD * 40];
  __shared__ float sO[16][DD + 4];
  const int tid = threadIdx.x;
  const int m0 = blockIdx.x * 16;
  const int lane = tid & 63, w = tid >> 6;
  const int fr = lane & 15;
  const int fk = (lane >> 4) * 8;
  const int srow = tid >> 2;
  const int skq = (tid & 3) * 8;
  f32x4 acc[6] = {};
  for (int k0 = 0; k0 < DI; k0 += 32) {
    if (tid < 64) {
      float4 a0 = *(const float4*)&Y[(size_t)(m0 + srow) * DI + k0 + skq];
      float4 a1 = *(const float4*)&Y[(size_t)(m0 + srow) * DI + k0 + skq + 4];
      *(short8*)&sA[srow * 40 + skq] =
          short8{f2bf(a0.x), f2bf(a0.y), f2bf(a0.z), f2bf(a0.w),
                 f2bf(a1.x), f2bf(a1.y), f2bf(a1.z), f2bf(a1.w)};
    }
#pragma unroll
    for (int s = 0; s < 6; s++) {
      int idx = s * 2048 + tid * 8;
      int row = idx >> 5, kk = idx & 31;
      float4 b0 = *(const float4*)&W[(size_t)row * DI + k0 + kk];
      float4 b1 = *(const float4*)&W[(size_t)row * DI + k0 + kk + 4];
      *(short8*)&sB[row * 40 + kk] =
          short8{f2bf(b0.x), f2bf(b0.y), f2bf(b0.z), f2bf(b0.w),
                 f2bf(b1.x), f2bf(b1.y), f2bf(b1.z), f2bf(b1.w)};
    }
    __syncthreads();
    short8 af = *(const short8*)&sA[fr * 40 + fk];
#pragma unroll
    for (int j = 0; j < 6; j++) {
      short8 bf = *(const short8*)&sB[(w * 96 + j * 16 + fr) * 40 + fk];
      acc[j] = __builtin_amdgcn_mfma_f32_16x16x32_bf16(af, bf, acc[j], 0, 0, 0);
    }
    __syncthreads();
  }
#pragma unroll
  for (int j = 0; j < 6; j++)
#pragma unroll
    for (int q = 0; q < 4; q++) {
      int r = (lane >> 4) * 4 + q;
      int col = w * 96 + j * 16 + (lane & 15);
      sO[r][col] = acc[j][q];
    }
  __syncthreads();
  // residual + LN: 16 threads per token row, 24 cols each
  const int row = tid >> 4, cg = tid & 15;
  const size_t gm = (size_t)(m0 + row) * DD;
  float vbuf[24];
  float s = 0.f, sq = 0.f;
#pragma unroll
  for (int i = 0; i < 24; i++) {
    int col = cg * 24 + i;
    float v = res[gm + col] + sO[row][col];
    vbuf[i] = v; s += v; sq += v * v;
  }
#pragma unroll
  for (int o = 1; o < 16; o <<= 1) { s += __shfl_xor(s, o); sq += __shfl_xor(sq, o); }
  float mu = s * (1.f / 384.f);
  float var = sq * (1.f / 384.f) - mu * mu;
  float rs = rsqrtf(var + EPSV);
#pragma unroll
  for (int i = 0; i < 24; i++) {
    int col = cg * 24 + i;
    res[gm + col] = vbuf[i];
    u[gm + col] = (vbuf[i] - mu) * rs * nw[col] + nb[col];
  }
}

// ---------------------------------------------------------------------------
// res += hid; u = LN(res)*nw+nb   (layer 0 only)
// ---------------------------------------------------------------------------
__global__ __launch_bounds__(128) void k_addln(float* __restrict__ res,
                                               const float* __restrict__ hid,
                                               float* __restrict__ u,
                                               const float* __restrict__ nw,
                                               const float* __restrict__ nb) {
  const int t = blockIdx.x;
  const int tid = threadIdx.x;
  float r[3];
  float s = 0.f, sq = 0.f;
#pragma unroll
  for (int j = 0; j < 3; j++) {
    int d = tid + j * 128;
    float v = res[(size_t)t * DD + d] + hid[(size_t)t * DD + d];
    res[(size_t)t * DD + d] = v;
    r[j] = v;
    s += v; sq += v * v;
  }
#pragma unroll
  for (int o = 32; o > 0; o >>= 1) { s += __shfl_xor(s, o); sq += __shfl_xor(sq, o); }
  __shared__ float ls[2], lq[2];
  int w = tid >> 6;
  if ((tid & 63) == 0) { ls[w] = s; lq[w] = sq; }
  __syncthreads();
  float st = ls[0] + ls[1], qt = lq[0] + lq[1];
  float mu = st * (1.f / 384.f);
  float var = qt * (1.f / 384.f) - mu * mu;
  float rs = rsqrtf(var + EPSV);
#pragma unroll
  for (int j = 0; j < 3; j++) {
    int d = tid + j * 128;
    u[(size_t)t * DD + d] = (r[j] - mu) * rs * nw[d] + nb[d];
  }
}

// ---------------------------------------------------------------------------
// causal depthwise conv (k=4, left pad 3) + bias + SiLU
// ---------------------------------------------------------------------------
__global__ __launch_bounds__(256) void k_conv(const float* __restrict__ xz,
                                              const float* __restrict__ wc,
                                              const float* __restrict__ bc,
                                              float* __restrict__ xc) {
  int i = blockIdx.x * 256 + threadIdx.x;
  if (i >= TT * DI) return;
  int e = i % DI;
  int t = i / DI;
  int b = t / LL, l = t % LL;
  float4 w = *(const float4*)&wc[e * 4];
  float acc = bc[e];
  const float* base = xz + (size_t)(b * LL) * (2 * DI) + e;
  if (l >= 3) acc += base[(size_t)(l - 3) * (2 * DI)] * w.x;
  if (l >= 2) acc += base[(size_t)(l - 2) * (2 * DI)] * w.y;
  if (l >= 1) acc += base[(size_t)(l - 1) * (2 * DI)] * w.z;
  acc += base[(size_t)l * (2 * DI)] * w.w;
  xc[i] = acc * (1.f / (1.f + __expf(-acc)));
}

// ---------------------------------------------------------------------------
// scan pass 1 with fused dt projection (fp32): thread = (e, n-half).
// dt = softplus(dbl[:, :24] @ Wdt[e] + bias[e]) computed on the fly.
// ---------------------------------------------------------------------------
__global__ __launch_bounds__(256) void k_scan1(const float* __restrict__ xc,
                                               const float* __restrict__ dbl,
                                               const float* __restrict__ Wdt,
                                               const float* __restrict__ dtb,
                                               const float* __restrict__ Alog,
                                               float* __restrict__ Aprod,
                                               float* __restrict__ Hend) {
  const int tid = threadIdx.x;
  const int e = blockIdx.x * 128 + (tid >> 1);
  const int nh = tid & 1;
  const int b = blockIdx.y;
  const int c = blockIdx.z;
  float wr[24];
#pragma unroll
  for (int s = 0; s < 6; s++) {
    float4 v = *(const float4*)&Wdt[(size_t)e * DTR + s * 4];
    wr[s * 4 + 0] = v.x; wr[s * 4 + 1] = v.y; wr[s * 4 + 2] = v.z; wr[s * 4 + 3] = v.w;
  }
  const float bias = dtb[e];
  float4 al0 = *(const float4*)&Alog[(size_t)e * DSN + nh * 8];
  float4 al1 = *(const float4*)&Alog[(size_t)e * DSN + nh * 8 + 4];
  float negA[8] = {-__expf(al0.x), -__expf(al0.y), -__expf(al0.z), -__expf(al0.w),
                   -__expf(al1.x), -__expf(al1.y), -__expf(al1.z), -__expf(al1.w)};
  float h[8] = {};
  float asum = 0.f;
  const int l0 = c * CH;
  const int l1 = (l0 + CH < LL) ? (l0 + CH) : LL;
  const size_t tbase = (size_t)b * LL;
  for (int l = l0; l < l1; l++) {
    size_t t = tbase + l;
    const float* dr = dbl + t * 56;
    float v = bias;
#pragma unroll
    for (int s = 0; s < 6; s++) {
      float4 d4 = *(const float4*)&dr[s * 4];
      v += d4.x * wr[s * 4] + d4.y * wr[s * 4 + 1] + d4.z * wr[s * 4 + 2] + d4.w * wr[s * 4 + 3];
    }
    float dtv = (v > 20.f) ? v : __logf(1.f + __expf(v));
    float xcv = xc[t * DI + e];
    float4 B0 = *(const float4*)&dr[DTR + nh * 8];
    float4 B1 = *(const float4*)&dr[DTR + nh * 8 + 4];
    float dx = dtv * xcv;
    float Bv[8] = {B0.x, B0.y, B0.z, B0.w, B1.x, B1.y, B1.z, B1.w};
#pragma unroll
    for (int j = 0; j < 8; j++)
      h[j] = __expf(dtv * negA[j]) * h[j] + dx * Bv[j];
    asum += dtv;
  }
  size_t ci = (((size_t)c * BB + b) * DI + e) * DSN + nh * 8;
  *(float4*)&Aprod[ci] = float4{__expf(asum * negA[0]), __expf(asum * negA[1]),
                                __expf(asum * negA[2]), __expf(asum * negA[3])};
  *(float4*)&Aprod[ci + 4] = float4{__expf(asum * negA[4]), __expf(asum * negA[5]),
                                    __expf(asum * negA[6]), __expf(asum * negA[7])};
  *(float4*)&Hend[ci] = float4{h[0], h[1], h[2], h[3]};
  *(float4*)&Hend[ci + 4] = float4{h[4], h[5], h[6], h[7]};
}

// ---------------------------------------------------------------------------
// scan pass 2 with fused dt projection AND fused carry fold (reads Aprod/Hend
// of previous chunks). y written to its own buffer; gating fused.
// ---------------------------------------------------------------------------
__global__ __launch_bounds__(256) void k_scan2(const float* __restrict__ xc,
                                               const float* __restrict__ xz,
                                               const float* __restrict__ dbl,
                                               const float* __restrict__ Wdt,
                                               const float* __restrict__ dtb,
                                               const float* __restrict__ Alog,
                                               const float* __restrict__ Dp,
                                               const float* __restrict__ Aprod,
                                               const float* __restrict__ Hend,
                                               float* __restrict__ y) {
  const int tid = threadIdx.x;
  const int e = blockIdx.x * 128 + (tid >> 1);
  const int nh = tid & 1;
  const int b = blockIdx.y;
  const int c = blockIdx.z;
  float wr[24];
#pragma unroll
  for (int s = 0; s < 6; s++) {
    float4 v = *(const float4*)&Wdt[(size_t)e * DTR + s * 4];
    wr[s * 4 + 0] = v.x; wr[s * 4 + 1] = v.y; wr[s * 4 + 2] = v.z; wr[s * 4 + 3] = v.w;
  }
  const float bias = dtb[e];
  float4 al0 = *(const float4*)&Alog[(size_t)e * DSN + nh * 8];
  float4 al1 = *(const float4*)&Alog[(size_t)e * DSN + nh * 8 + 4];
  float negA[8] = {-__expf(al0.x), -__expf(al0.y), -__expf(al0.z), -__expf(al0.w),
                   -__expf(al1.x), -__expf(al1.y), -__expf(al1.z), -__expf(al1.w)};
  const float dpv = Dp[e];
  // carry fold over previous chunks
  float h[8] = {};
  const size_t cstride = (size_t)BB * DI * DSN;
  const size_t cbase = (((size_t)b * DI + e) * DSN) + nh * 8;
  for (int cp = 0; cp < c; cp++) {
    size_t ci = (size_t)cp * cstride + cbase;
    float4 a0 = *(const float4*)&Aprod[ci];
    float4 a1 = *(const float4*)&Aprod[ci + 4];
    float4 e0 = *(const float4*)&Hend[ci];
    float4 e1 = *(const float4*)&Hend[ci + 4];
    h[0] = a0.x * h[0] + e0.x; h[1] = a0.y * h[1] + e0.y;
    h[2] = a0.z * h[2] + e0.z; h[3] = a0.w * h[3] + e0.w;
    h[4] = a1.x * h[4] + e1.x; h[5] = a1.y * h[5] + e1.y;
    h[6] = a1.z * h[6] + e1.z; h[7] = a1.w * h[7] + e1.w;
  }
  const int l0 = c * CH;
  const int l1 = (l0 + CH < LL) ? (l0 + CH) : LL;
  const size_t tbase = (size_t)b * LL;
  for (int l = l0; l < l1; l++) {
    size_t t = tbase + l;
    const float* dr = dbl + t * 56;
    float v = bias;
#pragma unroll
    for (int s = 0; s < 6; s++) {
      float4 d4 = *(const float4*)&dr[s * 4];
      v += d4.x * wr[s * 4] + d4.y * wr[s * 4 + 1] + d4.z * wr[s * 4 + 2] + d4.w * wr[s * 4 + 3];
    }
    float dtv = (v > 20.f) ? v : __logf(1.f + __expf(v));
    float xcv = xc[t * DI + e];
    float zv = xz[t * (2 * DI) + DI + e];
    float4 B0 = *(const float4*)&dr[DTR + nh * 8];
    float4 B1 = *(const float4*)&dr[DTR + nh * 8 + 4];
    float4 C0 = *(const float4*)&dr[DTR + DSN + nh * 8];
    float4 C1 = *(const float4*)&dr[DTR + DSN + nh * 8 + 4];
    float dx = dtv * xcv;
    float Bv[8] = {B0.x, B0.y, B0.z, B0.w, B1.x, B1.y, B1.z, B1.w};
    float Cv[8] = {C0.x, C0.y, C0.z, C0.w, C1.x, C1.y, C1.z, C1.w};
    float acc = 0.f;
#pragma unroll
    for (int j = 0; j < 8; j++) {
      h[j] = __expf(dtv * negA[j]) * h[j] + dx * Bv[j];
      acc += h[j] * Cv[j];
    }
    acc += __shfl_xor(acc, 1);
    if (nh == 0) {
      float sz = zv * (1.f / (1.f + __expf(-zv)));
      y[t * DI + e] = (acc + xcv * dpv) * sz;
    }
  }
}

// ---------------------------------------------------------------------------
// final: LN(res[b,0]) -> head. grid (8, BB): 125 classes per block.
// ---------------------------------------------------------------------------
__global__ __launch_bounds__(256) void k_final(const float* __restrict__ res,
                                               const float* __restrict__ nfw,
                                               const float* __restrict__ nfb,
                                               const float* __restrict__ hw,
                                               const float* __restrict__ hb,
                                               float* __restrict__ out) {
  const int b = blockIdx.y;
  const int c0 = blockIdx.x * 125;
  const int tid = threadIdx.x;
  __shared__ float u0[DD];
  __shared__ float ls[4], lq[4];
  const size_t t0 = (size_t)b * LL * DD;
  float v0 = res[t0 + tid];
  float v1 = (tid < 128) ? res[t0 + 256 + tid] : 0.f;
  float s = v0 + v1, sq = v0 * v0 + v1 * v1;
#pragma unroll
  for (int o = 32; o > 0; o >>= 1) { s += __shfl_xor(s, o); sq += __shfl_xor(sq, o); }
  if ((tid & 63) == 0) { ls[tid >> 6] = s; lq[tid >> 6] = sq; }
  __syncthreads();
  float st = ls[0] + ls[1] + ls[2] + ls[3];
  float qt = lq[0] + lq[1] + lq[2] + lq[3];
  float mu = st * (1.f / 384.f);
  float var = qt * (1.f / 384.f) - mu * mu;
  float rs = rsqrtf(var + EPSV);
  u0[tid] = (v0 - mu) * rs * nfw[tid] + nfb[tid];
  if (tid < 128) u0[256 + tid] = (v1 - mu) * rs * nfw[256 + tid] + nfb[256 + tid];
  __syncthreads();
  int c = c0 + tid;
  if (tid < 125 && c < NC) {
    float acc = hb[c];
    const float* wrow = hw + (size_t)c * DD;
    for (int d = 0; d < DD; d += 4) {
      float4 w4 = *(const float4*)&wrow[d];
      acc += u0[d] * w4.x + u0[d + 1] * w4.y + u0[d + 2] * w4.z + u0[d + 3] * w4.w;
    }
    out[(size_t)b * NC + c] = acc;
  }
}

// ---------------------------------------------------------------------------
extern "C" void kernel_launch(void* const* d_in, const int* in_sizes, int n_in,
                              void* d_out, int out_size, void* d_ws, size_t ws_size,
                              hipStream_t stream) {
  const float* x       = (const float*)d_in[0];
  const float* patch_w = (const float*)d_in[1];
  const float* patch_b = (const float*)d_in[2];
  const float* cls     = (const float*)d_in[3];
  const float* pos     = (const float*)d_in[4];
  const float* in_proj = (const float*)d_in[5];
  const float* conv_w  = (const float*)d_in[6];
  const float* conv_b  = (const float*)d_in[7];
  const float* x_proj  = (const float*)d_in[8];
  const float* dt_w    = (const float*)d_in[9];
  const float* dt_b    = (const float*)d_in[10];
  const float* A_log   = (const float*)d_in[11];
  const float* D_ssm   = (const float*)d_in[12];
  const float* out_w   = (const float*)d_in[13];
  const float* norm_w  = (const float*)d_in[14];
  const float* norm_b  = (const float*)d_in[15];
  const float* normf_w = (const float*)d_in[16];
  const float* normf_b = (const float*)d_in[17];
  const float* head_w  = (const float*)d_in[18];
  const float* head_b  = (const float*)d_in[19];
  float* out = (float*)d_out;

  float* ws = (float*)d_ws;
  float* res = ws;  ws += (size_t)TT * DD;
  float* hid = ws;  ws += (size_t)TT * DD;   // patch out; Hend region (w/ u) in layers
  float* u   = ws;  ws += (size_t)TT * DD;
  float* xzb = ws;  ws += (size_t)TT * 2 * DI;
  float* xcb = ws;  ws += (size_t)TT * DI;
  float* dbl = ws;  ws += (size_t)TT * 56;
  float* yb  = ws;  ws += (size_t)TT * DI;
  float* crg = ws;  ws += (size_t)TT * DI;
  // Aprod: NCHUNK*BB*DI*DSN = 2.36M floats, fits crg (2.42M)
  float* Aprod = crg;
  // Hend: 2.36M floats, lives in hid+u (2.42M contiguous). hid dead after
  // addln0; u dead after each layer's in_proj; k_oproj rewrites u afterwards.
  float* Hend = hid;

  k_init<<<(TT * DD + 255) / 256, 256, 0, stream>>>(cls, pos, res, hid);
  k_patch<<<dim3(49, 6), 256, 0, stream>>>(x, patch_w, patch_b, pos, hid);
  k_addln<<<TT, 128, 0, stream>>>(res, hid, u, norm_w, norm_b);

  for (int layer = 0; layer < DEPTH; layer++) {
    // in_proj: u (3152,384) @ Win^T (1536,384) -> xz (3152,1536)
    k_gemm_mfma<<<dim3(50, 24), 256, 0, stream>>>(
        u, DD, in_proj + (size_t)layer * 2 * DI * DD, DD, xzb, 2 * DI, TT, 2 * DI, DD);
    k_conv<<<(TT * DI) / 256, 256, 0, stream>>>(xzb, conv_w + layer * DI * 4,
                                                conv_b + layer * DI, xcb);
    // x_proj: xc (3152,768) @ Wx^T (56,768) -> dbl (3152,56)
    k_xproj<<<dim3(TT / 16), 256, 0, stream>>>(
        xcb, x_proj + (size_t)layer * 56 * DI, dbl);
    // scan: pass1 (dt fused) -> pass2 (dt + carry + gating fused)
    k_scan1<<<dim3(DI / 128, BB, NCHUNK), 256, 0, stream>>>(
        xcb, dbl, dt_w + (size_t)layer * DI * DTR, dt_b + layer * DI,
        A_log + (size_t)layer * DI * DSN, Aprod, Hend);
    k_scan2<<<dim3(DI / 128, BB, NCHUNK), 256, 0, stream>>>(
        xcb, xzb, dbl, dt_w + (size_t)layer * DI * DTR, dt_b + layer * DI,
        A_log + (size_t)layer * DI * DSN, D_ssm + layer * DI, Aprod, Hend, yb);
    // out_proj + residual + next-layer LN (197 blocks)
    const float* nwn = (layer + 1 < DEPTH) ? (norm_w + (layer + 1) * DD) : normf_w;
    const float* nbn = (layer + 1 < DEPTH) ? (norm_b + (layer + 1) * DD) : normf_b;
    k_oproj<<<dim3(TT / 16), 256, 0, stream>>>(
        yb, out_w + (size_t)layer * DD * DI, res, u, nwn, nbn);
  }

  k_final<<<dim3(8, BB), 256, 0, stream>>>(res, normf_w, normf_b, head_w, head_b, out);
}

// Round 10
// 3587.122 us; speedup vs baseline: 1.1233x; 1.1233x over previous
//
#include <hip/hip_runtime.h>
#include <hip/hip_bf16.h>
#include <math.h>

// Model dims
#define BB     16
#define LL     197
#define DD     384
#define DEPTH  24
#define DI     768
#define DSN    16
#define DTR    24
#define NC     1000
#define TT     (BB*LL)      // 3152 tokens
#define NPATCH 196
#define EPSV   1e-5f

// chunked scan config: 12 chunks of 17 tokens (11*17=187, last=10)
#define NCHUNK 12
#define CH     17

typedef __attribute__((ext_vector_type(8))) short short8;
typedef __attribute__((ext_vector_type(4))) float f32x4;

__device__ __forceinline__ short f2bf(float f) {
  union { float f; unsigned u; } v; v.f = f;
  unsigned u = v.u + 0x7fffu + ((v.u >> 16) & 1u);
  return (short)(u >> 16);
}

// ---------------------------------------------------------------------------
// init: zero res, write cls token row of hid
// ---------------------------------------------------------------------------
__global__ __launch_bounds__(256) void k_init(const float* __restrict__ cls,
                                              const float* __restrict__ pos,
                                              float* __restrict__ res,
                                              float* __restrict__ hid) {
  int i = blockIdx.x * 256 + threadIdx.x;
  if (i < TT * DD) res[i] = 0.f;
  if (i < BB * DD) {
    int b = i / DD, d = i % DD;
    hid[(size_t)(b * LL) * DD + d] = cls[d] + pos[d];
  }
}

// ---------------------------------------------------------------------------
// patch embed: bf16 MFMA GEMM with fused im2col.
// ---------------------------------------------------------------------------
__global__ __launch_bounds__(256) void k_patch(const float* __restrict__ x,
                                               const float* __restrict__ pw,
                                               const float* __restrict__ pb,
                                               const float* __restrict__ pos,
                                               float* __restrict__ hid) {
  __shared__ short sA[64 * 40];
  __shared__ short sB[64 * 40];
  const int tid = threadIdx.x;
  const int m0 = blockIdx.x * 64, n0 = blockIdx.y * 64;
  const int srow = tid >> 2;
  const int skq = (tid & 3) * 8;
  const int lane = tid & 63, w = tid >> 6;
  const int wm = (w >> 1) * 32, wn = (w & 1) * 32;
  const int fr = lane & 15;
  const int fk = (lane >> 4) * 8;
  f32x4 acc[2][2] = {};
  const int m = m0 + srow;
  const int b = m / NPATCH;
  const int p = m % NPATCH;
  const int ph = p / 14, pwi = p % 14;
  const float* Wrow = pw + (size_t)(n0 + srow) * 768 + skq;
  for (int k0 = 0; k0 < 768; k0 += 32) {
    int k = k0 + skq;
    int c = k >> 8, rr = (k >> 4) & 15, kw = k & 15;
    const float* xrow = &x[(size_t)(((b * 3 + c) * 224) + (ph * 16 + rr)) * 224 +
                           (pwi * 16 + kw)];
    float4 a0 = *(const float4*)&xrow[0];
    float4 a1 = *(const float4*)&xrow[4];
    float4 b0 = *(const float4*)&Wrow[k0];
    float4 b1 = *(const float4*)&Wrow[k0 + 4];
    short8 av = {f2bf(a0.x), f2bf(a0.y), f2bf(a0.z), f2bf(a0.w),
                 f2bf(a1.x), f2bf(a1.y), f2bf(a1.z), f2bf(a1.w)};
    short8 bv = {f2bf(b0.x), f2bf(b0.y), f2bf(b0.z), f2bf(b0.w),
                 f2bf(b1.x), f2bf(b1.y), f2bf(b1.z), f2bf(b1.w)};
    *(short8*)&sA[srow * 40 + skq] = av;
    *(short8*)&sB[srow * 40 + skq] = bv;
    __syncthreads();
    short8 af0 = *(const short8*)&sA[(wm + fr) * 40 + fk];
    short8 af1 = *(const short8*)&sA[(wm + 16 + fr) * 40 + fk];
    short8 bf0 = *(const short8*)&sB[(wn + fr) * 40 + fk];
    short8 bf1 = *(const short8*)&sB[(wn + 16 + fr) * 40 + fk];
    acc[0][0] = __builtin_amdgcn_mfma_f32_16x16x32_bf16(af0, bf0, acc[0][0], 0, 0, 0);
    acc[0][1] = __builtin_amdgcn_mfma_f32_16x16x32_bf16(af0, bf1, acc[0][1], 0, 0, 0);
    acc[1][0] = __builtin_amdgcn_mfma_f32_16x16x32_bf16(af1, bf0, acc[1][0], 0, 0, 0);
    acc[1][1] = __builtin_amdgcn_mfma_f32_16x16x32_bf16(af1, bf1, acc[1][1], 0, 0, 0);
    __syncthreads();
  }
#pragma unroll
  for (int i = 0; i < 2; i++)
#pragma unroll
    for (int j = 0; j < 2; j++)
#pragma unroll
      for (int q = 0; q < 4; q++) {
        int mm = m0 + wm + i * 16 + (lane >> 4) * 4 + q;
        int nn = n0 + wn + j * 16 + (lane & 15);
        int b2 = mm / NPATCH, pp = mm % NPATCH;
        int tok = b2 * LL + 1 + pp;
        hid[(size_t)tok * DD + nn] = acc[i][j][q] + pb[nn] + pos[(size_t)(1 + pp) * DD + nn];
      }
}

// ---------------------------------------------------------------------------
// bf16 MFMA GEMM: C[M,N] = A[M,K] * W[N,K]^T  (in_proj, out_proj)
// ---------------------------------------------------------------------------
__global__ __launch_bounds__(256) void k_gemm_mfma(const float* __restrict__ A, int lda,
                                                   const float* __restrict__ W, int ldb,
                                                   float* __restrict__ C, int ldc,
                                                   int M, int N, int K) {
  __shared__ short sA[64 * 40];
  __shared__ short sB[64 * 40];
  const int tid = threadIdx.x;
  const int m0 = blockIdx.x * 64, n0 = blockIdx.y * 64;
  const int srow = tid >> 2;
  const int skq = (tid & 3) * 8;
  const int lane = tid & 63, w = tid >> 6;
  const int wm = (w >> 1) * 32, wn = (w & 1) * 32;
  const int fr = lane & 15;
  const int fk = (lane >> 4) * 8;
  f32x4 acc[2][2] = {};
  const int am = m0 + srow;
  const bool aok = am < M;
  const float* Arow = A + (size_t)am * lda + skq;
  const float* Wrow = W + (size_t)(n0 + srow) * ldb + skq;
  for (int k0 = 0; k0 < K; k0 += 32) {
    float4 a0 = {0, 0, 0, 0}, a1 = {0, 0, 0, 0};
    if (aok) {
      a0 = *(const float4*)&Arow[k0];
      a1 = *(const float4*)&Arow[k0 + 4];
    }
    float4 b0 = *(const float4*)&Wrow[k0];
    float4 b1 = *(const float4*)&Wrow[k0 + 4];
    short8 av = {f2bf(a0.x), f2bf(a0.y), f2bf(a0.z), f2bf(a0.w),
                 f2bf(a1.x), f2bf(a1.y), f2bf(a1.z), f2bf(a1.w)};
    short8 bv = {f2bf(b0.x), f2bf(b0.y), f2bf(b0.z), f2bf(b0.w),
                 f2bf(b1.x), f2bf(b1.y), f2bf(b1.z), f2bf(b1.w)};
    *(short8*)&sA[srow * 40 + skq] = av;
    *(short8*)&sB[srow * 40 + skq] = bv;
    __syncthreads();
    short8 af0 = *(const short8*)&sA[(wm + fr) * 40 + fk];
    short8 af1 = *(const short8*)&sA[(wm + 16 + fr) * 40 + fk];
    short8 bf0 = *(const short8*)&sB[(wn + fr) * 40 + fk];
    short8 bf1 = *(const short8*)&sB[(wn + 16 + fr) * 40 + fk];
    acc[0][0] = __builtin_amdgcn_mfma_f32_16x16x32_bf16(af0, bf0, acc[0][0], 0, 0, 0);
    acc[0][1] = __builtin_amdgcn_mfma_f32_16x16x32_bf16(af0, bf1, acc[0][1], 0, 0, 0);
    acc[1][0] = __builtin_amdgcn_mfma_f32_16x16x32_bf16(af1, bf0, acc[1][0], 0, 0, 0);
    acc[1][1] = __builtin_amdgcn_mfma_f32_16x16x32_bf16(af1, bf1, acc[1][1], 0, 0, 0);
    __syncthreads();
  }
#pragma unroll
  for (int i = 0; i < 2; i++)
#pragma unroll
    for (int j = 0; j < 2; j++)
#pragma unroll
      for (int q = 0; q < 4; q++) {
        int mm = m0 + wm + i * 16 + (lane >> 4) * 4 + q;
        int nn = n0 + wn + j * 16 + (lane & 15);
        if (mm < M) C[(size_t)mm * ldc + nn] = acc[i][j][q];
      }
}

// ---------------------------------------------------------------------------
// x_proj: bf16 MFMA, BM=16, N=56 padded to 64, K=768
// ---------------------------------------------------------------------------
__global__ __launch_bounds__(256) void k_xproj(const float* __restrict__ A,
                                               const float* __restrict__ W,
                                               float* __restrict__ C) {
  __shared__ short sA[16 * 40];
  __shared__ short sB[64 * 40];
  const int tid = threadIdx.x;
  const int m0 = blockIdx.x * 16;
  const int lane = tid & 63, w = tid >> 6;
  const int wn = w * 16;
  const int fr = lane & 15;
  const int fk = (lane >> 4) * 8;
  const int srow = tid >> 2;
  const int skq = (tid & 3) * 8;
  f32x4 acc = {};
  for (int k0 = 0; k0 < DI; k0 += 32) {
    if (tid < 64) {
      float4 a0 = *(const float4*)&A[(size_t)(m0 + srow) * DI + k0 + skq];
      float4 a1 = *(const float4*)&A[(size_t)(m0 + srow) * DI + k0 + skq + 4];
      short8 av = {f2bf(a0.x), f2bf(a0.y), f2bf(a0.z), f2bf(a0.w),
                   f2bf(a1.x), f2bf(a1.y), f2bf(a1.z), f2bf(a1.w)};
      *(short8*)&sA[srow * 40 + skq] = av;
    }
    short8 bv = {0, 0, 0, 0, 0, 0, 0, 0};
    if (srow < 56) {
      float4 b0 = *(const float4*)&W[(size_t)srow * DI + k0 + skq];
      float4 b1 = *(const float4*)&W[(size_t)srow * DI + k0 + skq + 4];
      bv = short8{f2bf(b0.x), f2bf(b0.y), f2bf(b0.z), f2bf(b0.w),
                  f2bf(b1.x), f2bf(b1.y), f2bf(b1.z), f2bf(b1.w)};
    }
    *(short8*)&sB[srow * 40 + skq] = bv;
    __syncthreads();
    short8 af = *(const short8*)&sA[fr * 40 + fk];
    short8 bf = *(const short8*)&sB[(wn + fr) * 40 + fk];
    acc = __builtin_amdgcn_mfma_f32_16x16x32_bf16(af, bf, acc, 0, 0, 0);
    __syncthreads();
  }
#pragma unroll
  for (int q = 0; q < 4; q++) {
    int mm = m0 + (lane >> 4) * 4 + q;
    int nn = wn + (lane & 15);
    if (nn < 56) C[(size_t)mm * 56 + nn] = acc[q];
  }
}

// ---------------------------------------------------------------------------
// res += hid; u = LN(res)*nw+nb
// ---------------------------------------------------------------------------
__global__ __launch_bounds__(128) void k_addln(float* __restrict__ res,
                                               const float* __restrict__ hid,
                                               float* __restrict__ u,
                                               const float* __restrict__ nw,
                                               const float* __restrict__ nb) {
  const int t = blockIdx.x;
  const int tid = threadIdx.x;
  float r[3];
  float s = 0.f, sq = 0.f;
#pragma unroll
  for (int j = 0; j < 3; j++) {
    int d = tid + j * 128;
    float v = res[(size_t)t * DD + d] + hid[(size_t)t * DD + d];
    res[(size_t)t * DD + d] = v;
    r[j] = v;
    s += v; sq += v * v;
  }
#pragma unroll
  for (int o = 32; o > 0; o >>= 1) { s += __shfl_xor(s, o); sq += __shfl_xor(sq, o); }
  __shared__ float ls[2], lq[2];
  int w = tid >> 6;
  if ((tid & 63) == 0) { ls[w] = s; lq[w] = sq; }
  __syncthreads();
  float st = ls[0] + ls[1], qt = lq[0] + lq[1];
  float mu = st * (1.f / 384.f);
  float var = qt * (1.f / 384.f) - mu * mu;
  float rs = rsqrtf(var + EPSV);
#pragma unroll
  for (int j = 0; j < 3; j++) {
    int d = tid + j * 128;
    u[(size_t)t * DD + d] = (r[j] - mu) * rs * nw[d] + nb[d];
  }
}

// ---------------------------------------------------------------------------
// causal depthwise conv (k=4, left pad 3) + bias + SiLU
// ---------------------------------------------------------------------------
__global__ __launch_bounds__(256) void k_conv(const float* __restrict__ xz,
                                              const float* __restrict__ wc,
                                              const float* __restrict__ bc,
                                              float* __restrict__ xc) {
  int i = blockIdx.x * 256 + threadIdx.x;
  if (i >= TT * DI) return;
  int e = i % DI;
  int t = i / DI;
  int b = t / LL, l = t % LL;
  float4 w = *(const float4*)&wc[e * 4];
  float acc = bc[e];
  const float* base = xz + (size_t)(b * LL) * (2 * DI) + e;
  if (l >= 3) acc += base[(size_t)(l - 3) * (2 * DI)] * w.x;
  if (l >= 2) acc += base[(size_t)(l - 2) * (2 * DI)] * w.y;
  if (l >= 1) acc += base[(size_t)(l - 1) * (2 * DI)] * w.z;
  acc += base[(size_t)l * (2 * DI)] * w.w;
  xc[i] = acc * (1.f / (1.f + __expf(-acc)));
}

// ---------------------------------------------------------------------------
// scan pass 1 with fused dt projection (fp32): thread = (e, n-half).
// ---------------------------------------------------------------------------
__global__ __launch_bounds__(256) void k_scan1(const float* __restrict__ xc,
                                               const float* __restrict__ dbl,
                                               const float* __restrict__ Wdt,
                                               const float* __restrict__ dtb,
                                               const float* __restrict__ Alog,
                                               float* __restrict__ Aprod,
                                               float* __restrict__ Hend) {
  const int tid = threadIdx.x;
  const int e = blockIdx.x * 128 + (tid >> 1);
  const int nh = tid & 1;
  const int b = blockIdx.y;
  const int c = blockIdx.z;
  float wr[24];
#pragma unroll
  for (int s = 0; s < 6; s++) {
    float4 v = *(const float4*)&Wdt[(size_t)e * DTR + s * 4];
    wr[s * 4 + 0] = v.x; wr[s * 4 + 1] = v.y; wr[s * 4 + 2] = v.z; wr[s * 4 + 3] = v.w;
  }
  const float bias = dtb[e];
  float4 al0 = *(const float4*)&Alog[(size_t)e * DSN + nh * 8];
  float4 al1 = *(const float4*)&Alog[(size_t)e * DSN + nh * 8 + 4];
  float negA[8] = {-__expf(al0.x), -__expf(al0.y), -__expf(al0.z), -__expf(al0.w),
                   -__expf(al1.x), -__expf(al1.y), -__expf(al1.z), -__expf(al1.w)};
  float h[8] = {};
  float asum = 0.f;
  const int l0 = c * CH;
  const int l1 = (l0 + CH < LL) ? (l0 + CH) : LL;
  const size_t tbase = (size_t)b * LL;
  for (int l = l0; l < l1; l++) {
    size_t t = tbase + l;
    const float* dr = dbl + t * 56;
    float v = bias;
#pragma unroll
    for (int s = 0; s < 6; s++) {
      float4 d4 = *(const float4*)&dr[s * 4];
      v += d4.x * wr[s * 4] + d4.y * wr[s * 4 + 1] + d4.z * wr[s * 4 + 2] + d4.w * wr[s * 4 + 3];
    }
    float dtv = (v > 20.f) ? v : __logf(1.f + __expf(v));
    float xcv = xc[t * DI + e];
    float4 B0 = *(const float4*)&dr[DTR + nh * 8];
    float4 B1 = *(const float4*)&dr[DTR + nh * 8 + 4];
    float dx = dtv * xcv;
    float Bv[8] = {B0.x, B0.y, B0.z, B0.w, B1.x, B1.y, B1.z, B1.w};
#pragma unroll
    for (int j = 0; j < 8; j++)
      h[j] = __expf(dtv * negA[j]) * h[j] + dx * Bv[j];
    asum += dtv;
  }
  size_t ci = (((size_t)c * BB + b) * DI + e) * DSN + nh * 8;
  *(float4*)&Aprod[ci] = float4{__expf(asum * negA[0]), __expf(asum * negA[1]),
                                __expf(asum * negA[2]), __expf(asum * negA[3])};
  *(float4*)&Aprod[ci + 4] = float4{__expf(asum * negA[4]), __expf(asum * negA[5]),
                                    __expf(asum * negA[6]), __expf(asum * negA[7])};
  *(float4*)&Hend[ci] = float4{h[0], h[1], h[2], h[3]};
  *(float4*)&Hend[ci + 4] = float4{h[4], h[5], h[6], h[7]};
}

// ---------------------------------------------------------------------------
// scan pass 2: fused dt projection + fused carry fold + gating -> y buffer
// ---------------------------------------------------------------------------
__global__ __launch_bounds__(256) void k_scan2(const float* __restrict__ xc,
                                               const float* __restrict__ xz,
                                               const float* __restrict__ dbl,
                                               const float* __restrict__ Wdt,
                                               const float* __restrict__ dtb,
                                               const float* __restrict__ Alog,
                                               const float* __restrict__ Dp,
                                               const float* __restrict__ Aprod,
                                               const float* __restrict__ Hend,
                                               float* __restrict__ y) {
  const int tid = threadIdx.x;
  const int e = blockIdx.x * 128 + (tid >> 1);
  const int nh = tid & 1;
  const int b = blockIdx.y;
  const int c = blockIdx.z;
  float wr[24];
#pragma unroll
  for (int s = 0; s < 6; s++) {
    float4 v = *(const float4*)&Wdt[(size_t)e * DTR + s * 4];
    wr[s * 4 + 0] = v.x; wr[s * 4 + 1] = v.y; wr[s * 4 + 2] = v.z; wr[s * 4 + 3] = v.w;
  }
  const float bias = dtb[e];
  float4 al0 = *(const float4*)&Alog[(size_t)e * DSN + nh * 8];
  float4 al1 = *(const float4*)&Alog[(size_t)e * DSN + nh * 8 + 4];
  float negA[8] = {-__expf(al0.x), -__expf(al0.y), -__expf(al0.z), -__expf(al0.w),
                   -__expf(al1.x), -__expf(al1.y), -__expf(al1.z), -__expf(al1.w)};
  const float dpv = Dp[e];
  float h[8] = {};
  const size_t cstride = (size_t)BB * DI * DSN;
  const size_t cbase = (((size_t)b * DI + e) * DSN) + nh * 8;
  for (int cp = 0; cp < c; cp++) {
    size_t ci = (size_t)cp * cstride + cbase;
    float4 a0 = *(const float4*)&Aprod[ci];
    float4 a1 = *(const float4*)&Aprod[ci + 4];
    float4 e0 = *(const float4*)&Hend[ci];
    float4 e1 = *(const float4*)&Hend[ci + 4];
    h[0] = a0.x * h[0] + e0.x; h[1] = a0.y * h[1] + e0.y;
    h[2] = a0.z * h[2] + e0.z; h[3] = a0.w * h[3] + e0.w;
    h[4] = a1.x * h[4] + e1.x; h[5] = a1.y * h[5] + e1.y;
    h[6] = a1.z * h[6] + e1.z; h[7] = a1.w * h[7] + e1.w;
  }
  const int l0 = c * CH;
  const int l1 = (l0 + CH < LL) ? (l0 + CH) : LL;
  const size_t tbase = (size_t)b * LL;
  for (int l = l0; l < l1; l++) {
    size_t t = tbase + l;
    const float* dr = dbl + t * 56;
    float v = bias;
#pragma unroll
    for (int s = 0; s < 6; s++) {
      float4 d4 = *(const float4*)&dr[s * 4];
      v += d4.x * wr[s * 4] + d4.y * wr[s * 4 + 1] + d4.z * wr[s * 4 + 2] + d4.w * wr[s * 4 + 3];
    }
    float dtv = (v > 20.f) ? v : __logf(1.f + __expf(v));
    float xcv = xc[t * DI + e];
    float zv = xz[t * (2 * DI) + DI + e];
    float4 B0 = *(const float4*)&dr[DTR + nh * 8];
    float4 B1 = *(const float4*)&dr[DTR + nh * 8 + 4];
    float4 C0 = *(const float4*)&dr[DTR + DSN + nh * 8];
    float4 C1 = *(const float4*)&dr[DTR + DSN + nh * 8 + 4];
    float dx = dtv * xcv;
    float Bv[8] = {B0.x, B0.y, B0.z, B0.w, B1.x, B1.y, B1.z, B1.w};
    float Cv[8] = {C0.x, C0.y, C0.z, C0.w, C1.x, C1.y, C1.z, C1.w};
    float acc = 0.f;
#pragma unroll
    for (int j = 0; j < 8; j++) {
      h[j] = __expf(dtv * negA[j]) * h[j] + dx * Bv[j];
      acc += h[j] * Cv[j];
    }
    acc += __shfl_xor(acc, 1);
    if (nh == 0) {
      float sz = zv * (1.f / (1.f + __expf(-zv)));
      y[t * DI + e] = (acc + xcv * dpv) * sz;
    }
  }
}

// ---------------------------------------------------------------------------
// final: LN(res[b,0] + hid[b,0]) -> head. grid (8, BB): 125 classes/block.
// NOTE: hid holds the layer-24 out_proj output; the final residual add
// res+hid happens HERE (this was the R8/R9 bug: k_final read only res).
// ---------------------------------------------------------------------------
__global__ __launch_bounds__(256) void k_final(const float* __restrict__ res,
                                               const float* __restrict__ hid,
                                               const float* __restrict__ nfw,
                                               const float* __restrict__ nfb,
                                               const float* __restrict__ hw,
                                               const float* __restrict__ hb,
                                               float* __restrict__ out) {
  const int b = blockIdx.y;
  const int c0 = blockIdx.x * 125;
  const int tid = threadIdx.x;
  __shared__ float u0[DD];
  __shared__ float ls[4], lq[4];
  const size_t t0 = (size_t)b * LL * DD;
  float v0 = res[t0 + tid] + hid[t0 + tid];
  float v1 = (tid < 128) ? (res[t0 + 256 + tid] + hid[t0 + 256 + tid]) : 0.f;
  float s = v0 + v1, sq = v0 * v0 + v1 * v1;
#pragma unroll
  for (int o = 32; o > 0; o >>= 1) { s += __shfl_xor(s, o); sq += __shfl_xor(sq, o); }
  if ((tid & 63) == 0) { ls[tid >> 6] = s; lq[tid >> 6] = sq; }
  __syncthreads();
  float st = ls[0] + ls[1] + ls[2] + ls[3];
  float qt = lq[0] + lq[1] + lq[2] + lq[3];
  float mu = st * (1.f / 384.f);
  float var = qt * (1.f / 384.f) - mu * mu;
  float rs = rsqrtf(var + EPSV);
  u0[tid] = (v0 - mu) * rs * nfw[tid] + nfb[tid];
  if (tid < 128) u0[256 + tid] = (v1 - mu) * rs * nfw[256 + tid] + nfb[256 + tid];
  __syncthreads();
  int c = c0 + tid;
  if (tid < 125 && c < NC) {
    float acc = hb[c];
    const float* wrow = hw + (size_t)c * DD;
    for (int d = 0; d < DD; d += 4) {
      float4 w4 = *(const float4*)&wrow[d];
      acc += u0[d] * w4.x + u0[d + 1] * w4.y + u0[d + 2] * w4.z + u0[d + 3] * w4.w;
    }
    out[(size_t)b * NC + c] = acc;
  }
}

// ---------------------------------------------------------------------------
extern "C" void kernel_launch(void* const* d_in, const int* in_sizes, int n_in,
                              void* d_out, int out_size, void* d_ws, size_t ws_size,
                              hipStream_t stream) {
  const float* x       = (const float*)d_in[0];
  const float* patch_w = (const float*)d_in[1];
  const float* patch_b = (const float*)d_in[2];
  const float* cls     = (const float*)d_in[3];
  const float* pos     = (const float*)d_in[4];
  const float* in_proj = (const float*)d_in[5];
  const float* conv_w  = (const float*)d_in[6];
  const float* conv_b  = (const float*)d_in[7];
  const float* x_proj  = (const float*)d_in[8];
  const float* dt_w    = (const float*)d_in[9];
  const float* dt_b    = (const float*)d_in[10];
  const float* A_log   = (const float*)d_in[11];
  const float* D_ssm   = (const float*)d_in[12];
  const float* out_w   = (const float*)d_in[13];
  const float* norm_w  = (const float*)d_in[14];
  const float* norm_b  = (const float*)d_in[15];
  const float* normf_w = (const float*)d_in[16];
  const float* normf_b = (const float*)d_in[17];
  const float* head_w  = (const float*)d_in[18];
  const float* head_b  = (const float*)d_in[19];
  float* out = (float*)d_out;

  float* ws = (float*)d_ws;
  float* res = ws;  ws += (size_t)TT * DD;
  float* hid = ws;  ws += (size_t)TT * DD;   // out_proj out; Hend (w/ u) mid-layer
  float* u   = ws;  ws += (size_t)TT * DD;
  float* xzb = ws;  ws += (size_t)TT * 2 * DI;
  float* xcb = ws;  ws += (size_t)TT * DI;
  float* dbl = ws;  ws += (size_t)TT * 56;
  float* yb  = ws;  ws += (size_t)TT * DI;
  float* crg = ws;  ws += (size_t)TT * DI;
  // Aprod: NCHUNK*BB*DI*DSN = 2.36M floats <= crg (2.42M)
  float* Aprod = crg;
  // Hend: 2.36M floats in hid+u (2.42M contiguous). hid is read by addln
  // (layer start) BEFORE scan1 clobbers it; rewritten fully by out_proj
  // (layer end). u is consumed by in_proj before scan1.
  float* Hend = hid;

  k_init<<<(TT * DD + 255) / 256, 256, 0, stream>>>(cls, pos, res, hid);
  k_patch<<<dim3(49, 6), 256, 0, stream>>>(x, patch_w, patch_b, pos, hid);

  for (int layer = 0; layer < DEPTH; layer++) {
    k_addln<<<TT, 128, 0, stream>>>(res, hid, u, norm_w + layer * DD, norm_b + layer * DD);
    // in_proj: u (3152,384) @ Win^T (1536,384) -> xz (3152,1536)
    k_gemm_mfma<<<dim3(50, 24), 256, 0, stream>>>(
        u, DD, in_proj + (size_t)layer * 2 * DI * DD, DD, xzb, 2 * DI, TT, 2 * DI, DD);
    k_conv<<<(TT * DI) / 256, 256, 0, stream>>>(xzb, conv_w + layer * DI * 4,
                                                conv_b + layer * DI, xcb);
    // x_proj: xc (3152,768) @ Wx^T (56,768) -> dbl (3152,56)
    k_xproj<<<dim3(TT / 16), 256, 0, stream>>>(
        xcb, x_proj + (size_t)layer * 56 * DI, dbl);
    // scan: pass1 (dt fused) -> pass2 (dt + carry + gating fused) -> yb
    k_scan1<<<dim3(DI / 128, BB, NCHUNK), 256, 0, stream>>>(
        xcb, dbl, dt_w + (size_t)layer * DI * DTR, dt_b + layer * DI,
        A_log + (size_t)layer * DI * DSN, Aprod, Hend);
    k_scan2<<<dim3(DI / 128, BB, NCHUNK), 256, 0, stream>>>(
        xcb, xzb, dbl, dt_w + (size_t)layer * DI * DTR, dt_b + layer * DI,
        A_log + (size_t)layer * DI * DSN, D_ssm + layer * DI, Aprod, Hend, yb);
    // out_proj: y (3152,768) @ Wout^T (384,768) -> hid
    k_gemm_mfma<<<dim3(50, 6), 256, 0, stream>>>(
        yb, DI, out_w + (size_t)layer * DD * DI, DI, hid, DD, TT, DD, DI);
  }

  k_final<<<dim3(8, BB), 256, 0, stream>>>(res, hid, normf_w, normf_b, head_w, head_b, out);
}

// Round 11
// 3458.937 us; speedup vs baseline: 1.1649x; 1.0371x over previous
//
#include <hip/hip_runtime.h>
#include <hip/hip_bf16.h>
#include <math.h>

// Model dims
#define BB     16
#define LL     197
#define DD     384
#define DEPTH  24
#define DI     768
#define DSN    16
#define DTR    24
#define NC     1000
#define TT     (BB*LL)      // 3152 tokens
#define NPATCH 196
#define EPSV   1e-5f

// chunked scan config: 12 chunks of 17 tokens (11*17=187, last=10)
#define NCHUNK 12
#define CH     17

typedef __attribute__((ext_vector_type(8))) short short8;
typedef __attribute__((ext_vector_type(4))) float f32x4;

__device__ __forceinline__ short f2bf(float f) {
  union { float f; unsigned u; } v; v.f = f;
  unsigned u = v.u + 0x7fffu + ((v.u >> 16) & 1u);
  return (short)(u >> 16);
}

// ---------------------------------------------------------------------------
// init: zero res, write cls token row of hid
// ---------------------------------------------------------------------------
__global__ __launch_bounds__(256) void k_init(const float* __restrict__ cls,
                                              const float* __restrict__ pos,
                                              float* __restrict__ res,
                                              float* __restrict__ hid) {
  int i = blockIdx.x * 256 + threadIdx.x;
  if (i < TT * DD) res[i] = 0.f;
  if (i < BB * DD) {
    int b = i / DD, d = i % DD;
    hid[(size_t)(b * LL) * DD + d] = cls[d] + pos[d];
  }
}

// ---------------------------------------------------------------------------
// patch embed: bf16 MFMA GEMM with fused im2col.
// ---------------------------------------------------------------------------
__global__ __launch_bounds__(256) void k_patch(const float* __restrict__ x,
                                               const float* __restrict__ pw,
                                               const float* __restrict__ pb,
                                               const float* __restrict__ pos,
                                               float* __restrict__ hid) {
  __shared__ short sA[64 * 40];
  __shared__ short sB[64 * 40];
  const int tid = threadIdx.x;
  const int m0 = blockIdx.x * 64, n0 = blockIdx.y * 64;
  const int srow = tid >> 2;
  const int skq = (tid & 3) * 8;
  const int lane = tid & 63, w = tid >> 6;
  const int wm = (w >> 1) * 32, wn = (w & 1) * 32;
  const int fr = lane & 15;
  const int fk = (lane >> 4) * 8;
  f32x4 acc[2][2] = {};
  const int m = m0 + srow;
  const int b = m / NPATCH;
  const int p = m % NPATCH;
  const int ph = p / 14, pwi = p % 14;
  const float* Wrow = pw + (size_t)(n0 + srow) * 768 + skq;
  for (int k0 = 0; k0 < 768; k0 += 32) {
    int k = k0 + skq;
    int c = k >> 8, rr = (k >> 4) & 15, kw = k & 15;
    const float* xrow = &x[(size_t)(((b * 3 + c) * 224) + (ph * 16 + rr)) * 224 +
                           (pwi * 16 + kw)];
    float4 a0 = *(const float4*)&xrow[0];
    float4 a1 = *(const float4*)&xrow[4];
    float4 b0 = *(const float4*)&Wrow[k0];
    float4 b1 = *(const float4*)&Wrow[k0 + 4];
    short8 av = {f2bf(a0.x), f2bf(a0.y), f2bf(a0.z), f2bf(a0.w),
                 f2bf(a1.x), f2bf(a1.y), f2bf(a1.z), f2bf(a1.w)};
    short8 bv = {f2bf(b0.x), f2bf(b0.y), f2bf(b0.z), f2bf(b0.w),
                 f2bf(b1.x), f2bf(b1.y), f2bf(b1.z), f2bf(b1.w)};
    *(short8*)&sA[srow * 40 + skq] = av;
    *(short8*)&sB[srow * 40 + skq] = bv;
    __syncthreads();
    short8 af0 = *(const short8*)&sA[(wm + fr) * 40 + fk];
    short8 af1 = *(const short8*)&sA[(wm + 16 + fr) * 40 + fk];
    short8 bf0 = *(const short8*)&sB[(wn + fr) * 40 + fk];
    short8 bf1 = *(const short8*)&sB[(wn + 16 + fr) * 40 + fk];
    acc[0][0] = __builtin_amdgcn_mfma_f32_16x16x32_bf16(af0, bf0, acc[0][0], 0, 0, 0);
    acc[0][1] = __builtin_amdgcn_mfma_f32_16x16x32_bf16(af0, bf1, acc[0][1], 0, 0, 0);
    acc[1][0] = __builtin_amdgcn_mfma_f32_16x16x32_bf16(af1, bf0, acc[1][0], 0, 0, 0);
    acc[1][1] = __builtin_amdgcn_mfma_f32_16x16x32_bf16(af1, bf1, acc[1][1], 0, 0, 0);
    __syncthreads();
  }
#pragma unroll
  for (int i = 0; i < 2; i++)
#pragma unroll
    for (int j = 0; j < 2; j++)
#pragma unroll
      for (int q = 0; q < 4; q++) {
        int mm = m0 + wm + i * 16 + (lane >> 4) * 4 + q;
        int nn = n0 + wn + j * 16 + (lane & 15);
        int b2 = mm / NPATCH, pp = mm % NPATCH;
        int tok = b2 * LL + 1 + pp;
        hid[(size_t)tok * DD + nn] = acc[i][j][q] + pb[nn] + pos[(size_t)(1 + pp) * DD + nn];
      }
}

// ---------------------------------------------------------------------------
// bf16 MFMA GEMM: C[M,N] = A[M,K] * W[N,K]^T  (in_proj, out_proj)
// ---------------------------------------------------------------------------
__global__ __launch_bounds__(256) void k_gemm_mfma(const float* __restrict__ A, int lda,
                                                   const float* __restrict__ W, int ldb,
                                                   float* __restrict__ C, int ldc,
                                                   int M, int N, int K) {
  __shared__ short sA[64 * 40];
  __shared__ short sB[64 * 40];
  const int tid = threadIdx.x;
  const int m0 = blockIdx.x * 64, n0 = blockIdx.y * 64;
  const int srow = tid >> 2;
  const int skq = (tid & 3) * 8;
  const int lane = tid & 63, w = tid >> 6;
  const int wm = (w >> 1) * 32, wn = (w & 1) * 32;
  const int fr = lane & 15;
  const int fk = (lane >> 4) * 8;
  f32x4 acc[2][2] = {};
  const int am = m0 + srow;
  const bool aok = am < M;
  const float* Arow = A + (size_t)am * lda + skq;
  const float* Wrow = W + (size_t)(n0 + srow) * ldb + skq;
  for (int k0 = 0; k0 < K; k0 += 32) {
    float4 a0 = {0, 0, 0, 0}, a1 = {0, 0, 0, 0};
    if (aok) {
      a0 = *(const float4*)&Arow[k0];
      a1 = *(const float4*)&Arow[k0 + 4];
    }
    float4 b0 = *(const float4*)&Wrow[k0];
    float4 b1 = *(const float4*)&Wrow[k0 + 4];
    short8 av = {f2bf(a0.x), f2bf(a0.y), f2bf(a0.z), f2bf(a0.w),
                 f2bf(a1.x), f2bf(a1.y), f2bf(a1.z), f2bf(a1.w)};
    short8 bv = {f2bf(b0.x), f2bf(b0.y), f2bf(b0.z), f2bf(b0.w),
                 f2bf(b1.x), f2bf(b1.y), f2bf(b1.z), f2bf(b1.w)};
    *(short8*)&sA[srow * 40 + skq] = av;
    *(short8*)&sB[srow * 40 + skq] = bv;
    __syncthreads();
    short8 af0 = *(const short8*)&sA[(wm + fr) * 40 + fk];
    short8 af1 = *(const short8*)&sA[(wm + 16 + fr) * 40 + fk];
    short8 bf0 = *(const short8*)&sB[(wn + fr) * 40 + fk];
    short8 bf1 = *(const short8*)&sB[(wn + 16 + fr) * 40 + fk];
    acc[0][0] = __builtin_amdgcn_mfma_f32_16x16x32_bf16(af0, bf0, acc[0][0], 0, 0, 0);
    acc[0][1] = __builtin_amdgcn_mfma_f32_16x16x32_bf16(af0, bf1, acc[0][1], 0, 0, 0);
    acc[1][0] = __builtin_amdgcn_mfma_f32_16x16x32_bf16(af1, bf0, acc[1][0], 0, 0, 0);
    acc[1][1] = __builtin_amdgcn_mfma_f32_16x16x32_bf16(af1, bf1, acc[1][1], 0, 0, 0);
    __syncthreads();
  }
#pragma unroll
  for (int i = 0; i < 2; i++)
#pragma unroll
    for (int j = 0; j < 2; j++)
#pragma unroll
      for (int q = 0; q < 4; q++) {
        int mm = m0 + wm + i * 16 + (lane >> 4) * 4 + q;
        int nn = n0 + wn + j * 16 + (lane & 15);
        if (mm < M) C[(size_t)mm * ldc + nn] = acc[i][j][q];
      }
}

// ---------------------------------------------------------------------------
// dt projection: bf16 MFMA, K=24 padded to 32 (1 k-iter), softplus epilogue.
// dt written to C (ldc=DI).  [R4-R6 proven]
// ---------------------------------------------------------------------------
__global__ __launch_bounds__(256) void k_dtproj(const float* __restrict__ A,
                                                const float* __restrict__ W,
                                                const float* __restrict__ bias,
                                                float* __restrict__ C) {
  __shared__ short sA[64 * 40];
  __shared__ short sB[64 * 40];
  const int tid = threadIdx.x;
  const int m0 = blockIdx.x * 64, n0 = blockIdx.y * 64;
  const int srow = tid >> 2;
  const int skq = (tid & 3) * 8;
  const int lane = tid & 63, w = tid >> 6;
  const int wm = (w >> 1) * 32, wn = (w & 1) * 32;
  const int fr = lane & 15;
  const int fk = (lane >> 4) * 8;
  f32x4 acc[2][2] = {};
  const int am = m0 + srow;
  short8 av = {0, 0, 0, 0, 0, 0, 0, 0}, bv = {0, 0, 0, 0, 0, 0, 0, 0};
  if (skq < 24) {
    if (am < TT) {
      float4 a0 = *(const float4*)&A[(size_t)am * 56 + skq];
      float4 a1 = *(const float4*)&A[(size_t)am * 56 + skq + 4];
      av = short8{f2bf(a0.x), f2bf(a0.y), f2bf(a0.z), f2bf(a0.w),
                  f2bf(a1.x), f2bf(a1.y), f2bf(a1.z), f2bf(a1.w)};
    }
    float4 b0 = *(const float4*)&W[(size_t)(n0 + srow) * 24 + skq];
    float4 b1 = *(const float4*)&W[(size_t)(n0 + srow) * 24 + skq + 4];
    bv = short8{f2bf(b0.x), f2bf(b0.y), f2bf(b0.z), f2bf(b0.w),
                f2bf(b1.x), f2bf(b1.y), f2bf(b1.z), f2bf(b1.w)};
  }
  *(short8*)&sA[srow * 40 + skq] = av;
  *(short8*)&sB[srow * 40 + skq] = bv;
  __syncthreads();
  short8 af0 = *(const short8*)&sA[(wm + fr) * 40 + fk];
  short8 af1 = *(const short8*)&sA[(wm + 16 + fr) * 40 + fk];
  short8 bf0 = *(const short8*)&sB[(wn + fr) * 40 + fk];
  short8 bf1 = *(const short8*)&sB[(wn + 16 + fr) * 40 + fk];
  acc[0][0] = __builtin_amdgcn_mfma_f32_16x16x32_bf16(af0, bf0, acc[0][0], 0, 0, 0);
  acc[0][1] = __builtin_amdgcn_mfma_f32_16x16x32_bf16(af0, bf1, acc[0][1], 0, 0, 0);
  acc[1][0] = __builtin_amdgcn_mfma_f32_16x16x32_bf16(af1, bf0, acc[1][0], 0, 0, 0);
  acc[1][1] = __builtin_amdgcn_mfma_f32_16x16x32_bf16(af1, bf1, acc[1][1], 0, 0, 0);
#pragma unroll
  for (int i = 0; i < 2; i++)
#pragma unroll
    for (int j = 0; j < 2; j++)
#pragma unroll
      for (int q = 0; q < 4; q++) {
        int mm = m0 + wm + i * 16 + (lane >> 4) * 4 + q;
        int nn = n0 + wn + j * 16 + (lane & 15);
        if (mm < TT) {
          float v = acc[i][j][q] + bias[nn];
          v = (v > 20.f) ? v : log1pf(__expf(v));
          C[(size_t)mm * DI + nn] = v;
        }
      }
}

// ---------------------------------------------------------------------------
// x_proj: bf16 MFMA, BM=16, N=56 padded to 64, K=768
// ---------------------------------------------------------------------------
__global__ __launch_bounds__(256) void k_xproj(const float* __restrict__ A,
                                               const float* __restrict__ W,
                                               float* __restrict__ C) {
  __shared__ short sA[16 * 40];
  __shared__ short sB[64 * 40];
  const int tid = threadIdx.x;
  const int m0 = blockIdx.x * 16;
  const int lane = tid & 63, w = tid >> 6;
  const int wn = w * 16;
  const int fr = lane & 15;
  const int fk = (lane >> 4) * 8;
  const int srow = tid >> 2;
  const int skq = (tid & 3) * 8;
  f32x4 acc = {};
  for (int k0 = 0; k0 < DI; k0 += 32) {
    if (tid < 64) {
      float4 a0 = *(const float4*)&A[(size_t)(m0 + srow) * DI + k0 + skq];
      float4 a1 = *(const float4*)&A[(size_t)(m0 + srow) * DI + k0 + skq + 4];
      short8 av = {f2bf(a0.x), f2bf(a0.y), f2bf(a0.z), f2bf(a0.w),
                   f2bf(a1.x), f2bf(a1.y), f2bf(a1.z), f2bf(a1.w)};
      *(short8*)&sA[srow * 40 + skq] = av;
    }
    short8 bv = {0, 0, 0, 0, 0, 0, 0, 0};
    if (srow < 56) {
      float4 b0 = *(const float4*)&W[(size_t)srow * DI + k0 + skq];
      float4 b1 = *(const float4*)&W[(size_t)srow * DI + k0 + skq + 4];
      bv = short8{f2bf(b0.x), f2bf(b0.y), f2bf(b0.z), f2bf(b0.w),
                  f2bf(b1.x), f2bf(b1.y), f2bf(b1.z), f2bf(b1.w)};
    }
    *(short8*)&sB[srow * 40 + skq] = bv;
    __syncthreads();
    short8 af = *(const short8*)&sA[fr * 40 + fk];
    short8 bf = *(const short8*)&sB[(wn + fr) * 40 + fk];
    acc = __builtin_amdgcn_mfma_f32_16x16x32_bf16(af, bf, acc, 0, 0, 0);
    __syncthreads();
  }
#pragma unroll
  for (int q = 0; q < 4; q++) {
    int mm = m0 + (lane >> 4) * 4 + q;
    int nn = wn + (lane & 15);
    if (nn < 56) C[(size_t)mm * 56 + nn] = acc[q];
  }
}

// ---------------------------------------------------------------------------
// res += hid; u = LN(res)*nw+nb
// ---------------------------------------------------------------------------
__global__ __launch_bounds__(128) void k_addln(float* __restrict__ res,
                                               const float* __restrict__ hid,
                                               float* __restrict__ u,
                                               const float* __restrict__ nw,
                                               const float* __restrict__ nb) {
  const int t = blockIdx.x;
  const int tid = threadIdx.x;
  float r[3];
  float s = 0.f, sq = 0.f;
#pragma unroll
  for (int j = 0; j < 3; j++) {
    int d = tid + j * 128;
    float v = res[(size_t)t * DD + d] + hid[(size_t)t * DD + d];
    res[(size_t)t * DD + d] = v;
    r[j] = v;
    s += v; sq += v * v;
  }
#pragma unroll
  for (int o = 32; o > 0; o >>= 1) { s += __shfl_xor(s, o); sq += __shfl_xor(sq, o); }
  __shared__ float ls[2], lq[2];
  int w = tid >> 6;
  if ((tid & 63) == 0) { ls[w] = s; lq[w] = sq; }
  __syncthreads();
  float st = ls[0] + ls[1], qt = lq[0] + lq[1];
  float mu = st * (1.f / 384.f);
  float var = qt * (1.f / 384.f) - mu * mu;
  float rs = rsqrtf(var + EPSV);
#pragma unroll
  for (int j = 0; j < 3; j++) {
    int d = tid + j * 128;
    u[(size_t)t * DD + d] = (r[j] - mu) * rs * nw[d] + nb[d];
  }
}

// ---------------------------------------------------------------------------
// causal depthwise conv (k=4, left pad 3) + bias + SiLU — float4 vectorized
// ---------------------------------------------------------------------------
__global__ __launch_bounds__(256) void k_conv(const float* __restrict__ xz,
                                              const float* __restrict__ wc,
                                              const float* __restrict__ bc,
                                              float* __restrict__ xc) {
  int i = blockIdx.x * 256 + threadIdx.x;   // over TT*DI/4
  if (i >= TT * (DI / 4)) return;
  int eg = i % (DI / 4);
  int t = i / (DI / 4);
  int e = eg * 4;
  int b = t / LL, l = t % LL;
  const float* base = xz + (size_t)(b * LL) * (2 * DI) + e;
  float4 w0 = *(const float4*)&wc[(e + 0) * 4];
  float4 w1 = *(const float4*)&wc[(e + 1) * 4];
  float4 w2 = *(const float4*)&wc[(e + 2) * 4];
  float4 w3 = *(const float4*)&wc[(e + 3) * 4];
  float4 acc = *(const float4*)&bc[e];
  if (l >= 3) {
    float4 xv = *(const float4*)&base[(size_t)(l - 3) * (2 * DI)];
    acc.x += xv.x * w0.x; acc.y += xv.y * w1.x; acc.z += xv.z * w2.x; acc.w += xv.w * w3.x;
  }
  if (l >= 2) {
    float4 xv = *(const float4*)&base[(size_t)(l - 2) * (2 * DI)];
    acc.x += xv.x * w0.y; acc.y += xv.y * w1.y; acc.z += xv.z * w2.y; acc.w += xv.w * w3.y;
  }
  if (l >= 1) {
    float4 xv = *(const float4*)&base[(size_t)(l - 1) * (2 * DI)];
    acc.x += xv.x * w0.z; acc.y += xv.y * w1.z; acc.z += xv.z * w2.z; acc.w += xv.w * w3.z;
  }
  {
    float4 xv = *(const float4*)&base[(size_t)l * (2 * DI)];
    acc.x += xv.x * w0.w; acc.y += xv.y * w1.w; acc.z += xv.z * w2.w; acc.w += xv.w * w3.w;
  }
  acc.x = acc.x / (1.f + __expf(-acc.x));
  acc.y = acc.y / (1.f + __expf(-acc.y));
  acc.z = acc.z / (1.f + __expf(-acc.z));
  acc.w = acc.w / (1.f + __expf(-acc.w));
  *(float4*)&xc[(size_t)t * DI + e] = acc;
}

// ---------------------------------------------------------------------------
// lean scan pass 1 (R6-proven): register h[8], thread = (e, n-half).
// ---------------------------------------------------------------------------
__global__ __launch_bounds__(256) void k_scan1(const float* __restrict__ dt,
                                               const float* __restrict__ xc,
                                               const float* __restrict__ dbl,
                                               const float* __restrict__ Alog,
                                               float* __restrict__ Aprod,
                                               float* __restrict__ Hend) {
  const int tid = threadIdx.x;
  const int e = blockIdx.x * 128 + (tid >> 1);
  const int nh = tid & 1;
  const int b = blockIdx.y;
  const int c = blockIdx.z;
  float4 al0 = *(const float4*)&Alog[(size_t)e * DSN + nh * 8];
  float4 al1 = *(const float4*)&Alog[(size_t)e * DSN + nh * 8 + 4];
  float negA[8] = {-__expf(al0.x), -__expf(al0.y), -__expf(al0.z), -__expf(al0.w),
                   -__expf(al1.x), -__expf(al1.y), -__expf(al1.z), -__expf(al1.w)};
  float h[8] = {};
  float asum = 0.f;
  const int l0 = c * CH;
  const int l1 = (l0 + CH < LL) ? (l0 + CH) : LL;
  const size_t tbase = (size_t)b * LL;
  for (int l = l0; l < l1; l++) {
    size_t t = tbase + l;
    float dtv = dt[t * DI + e];
    float xcv = xc[t * DI + e];
    float4 B0 = *(const float4*)&dbl[t * 56 + DTR + nh * 8];
    float4 B1 = *(const float4*)&dbl[t * 56 + DTR + nh * 8 + 4];
    float dx = dtv * xcv;
    float Bv[8] = {B0.x, B0.y, B0.z, B0.w, B1.x, B1.y, B1.z, B1.w};
#pragma unroll
    for (int j = 0; j < 8; j++)
      h[j] = __expf(dtv * negA[j]) * h[j] + dx * Bv[j];
    asum += dtv;
  }
  size_t ci = (((size_t)c * BB + b) * DI + e) * DSN + nh * 8;
  *(float4*)&Aprod[ci] = float4{__expf(asum * negA[0]), __expf(asum * negA[1]),
                                __expf(asum * negA[2]), __expf(asum * negA[3])};
  *(float4*)&Aprod[ci + 4] = float4{__expf(asum * negA[4]), __expf(asum * negA[5]),
                                    __expf(asum * negA[6]), __expf(asum * negA[7])};
  *(float4*)&Hend[ci] = float4{h[0], h[1], h[2], h[3]};
  *(float4*)&Hend[ci + 4] = float4{h[4], h[5], h[6], h[7]};
}

// ---------------------------------------------------------------------------
// lean scan pass 2: carry fold (R10-proven) + recurrence + gating.
// y MAY alias dt (same-thread read-before-write per (t,e) — R6-proven).
// ---------------------------------------------------------------------------
__global__ __launch_bounds__(256) void k_scan2(const float* __restrict__ dt,
                                               const float* __restrict__ xc,
                                               const float* __restrict__ xz,
                                               const float* __restrict__ dbl,
                                               const float* __restrict__ Alog,
                                               const float* __restrict__ Dp,
                                               const float* __restrict__ Aprod,
                                               const float* __restrict__ Hend,
                                               float* __restrict__ y) {
  const int tid = threadIdx.x;
  const int e = blockIdx.x * 128 + (tid >> 1);
  const int nh = tid & 1;
  const int b = blockIdx.y;
  const int c = blockIdx.z;
  float4 al0 = *(const float4*)&Alog[(size_t)e * DSN + nh * 8];
  float4 al1 = *(const float4*)&Alog[(size_t)e * DSN + nh * 8 + 4];
  float negA[8] = {-__expf(al0.x), -__expf(al0.y), -__expf(al0.z), -__expf(al0.w),
                   -__expf(al1.x), -__expf(al1.y), -__expf(al1.z), -__expf(al1.w)};
  const float dpv = Dp[e];
  float h[8] = {};
  const size_t cstride = (size_t)BB * DI * DSN;
  const size_t cbase = (((size_t)b * DI + e) * DSN) + nh * 8;
  for (int cp = 0; cp < c; cp++) {
    size_t ci = (size_t)cp * cstride + cbase;
    float4 a0 = *(const float4*)&Aprod[ci];
    float4 a1 = *(const float4*)&Aprod[ci + 4];
    float4 e0 = *(const float4*)&Hend[ci];
    float4 e1 = *(const float4*)&Hend[ci + 4];
    h[0] = a0.x * h[0] + e0.x; h[1] = a0.y * h[1] + e0.y;
    h[2] = a0.z * h[2] + e0.z; h[3] = a0.w * h[3] + e0.w;
    h[4] = a1.x * h[4] + e1.x; h[5] = a1.y * h[5] + e1.y;
    h[6] = a1.z * h[6] + e1.z; h[7] = a1.w * h[7] + e1.w;
  }
  const int l0 = c * CH;
  const int l1 = (l0 + CH < LL) ? (l0 + CH) : LL;
  const size_t tbase = (size_t)b * LL;
  for (int l = l0; l < l1; l++) {
    size_t t = tbase + l;
    float dtv = dt[t * DI + e];
    float xcv = xc[t * DI + e];
    float zv = xz[t * (2 * DI) + DI + e];
    float4 B0 = *(const float4*)&dbl[t * 56 + DTR + nh * 8];
    float4 B1 = *(const float4*)&dbl[t * 56 + DTR + nh * 8 + 4];
    float4 C0 = *(const float4*)&dbl[t * 56 + DTR + DSN + nh * 8];
    float4 C1 = *(const float4*)&dbl[t * 56 + DTR + DSN + nh * 8 + 4];
    float dx = dtv * xcv;
    float Bv[8] = {B0.x, B0.y, B0.z, B0.w, B1.x, B1.y, B1.z, B1.w};
    float Cv[8] = {C0.x, C0.y, C0.z, C0.w, C1.x, C1.y, C1.z, C1.w};
    float acc = 0.f;
#pragma unroll
    for (int j = 0; j < 8; j++) {
      h[j] = __expf(dtv * negA[j]) * h[j] + dx * Bv[j];
      acc += h[j] * Cv[j];
    }
    acc += __shfl_xor(acc, 1);
    if (nh == 0) {
      float sz = zv * (1.f / (1.f + __expf(-zv)));
      y[t * DI + e] = (acc + xcv * dpv) * sz;
    }
  }
}

// ---------------------------------------------------------------------------
// final: LN(res[b,0] + hid[b,0]) -> head. grid (8, BB): 125 classes/block.
// ---------------------------------------------------------------------------
__global__ __launch_bounds__(256) void k_final(const float* __restrict__ res,
                                               const float* __restrict__ hid,
                                               const float* __restrict__ nfw,
                                               const float* __restrict__ nfb,
                                               const float* __restrict__ hw,
                                               const float* __restrict__ hb,
                                               float* __restrict__ out) {
  const int b = blockIdx.y;
  const int c0 = blockIdx.x * 125;
  const int tid = threadIdx.x;
  __shared__ float u0[DD];
  __shared__ float ls[4], lq[4];
  const size_t t0 = (size_t)b * LL * DD;
  float v0 = res[t0 + tid] + hid[t0 + tid];
  float v1 = (tid < 128) ? (res[t0 + 256 + tid] + hid[t0 + 256 + tid]) : 0.f;
  float s = v0 + v1, sq = v0 * v0 + v1 * v1;
#pragma unroll
  for (int o = 32; o > 0; o >>= 1) { s += __shfl_xor(s, o); sq += __shfl_xor(sq, o); }
  if ((tid & 63) == 0) { ls[tid >> 6] = s; lq[tid >> 6] = sq; }
  __syncthreads();
  float st = ls[0] + ls[1] + ls[2] + ls[3];
  float qt = lq[0] + lq[1] + lq[2] + lq[3];
  float mu = st * (1.f / 384.f);
  float var = qt * (1.f / 384.f) - mu * mu;
  float rs = rsqrtf(var + EPSV);
  u0[tid] = (v0 - mu) * rs * nfw[tid] + nfb[tid];
  if (tid < 128) u0[256 + tid] = (v1 - mu) * rs * nfw[256 + tid] + nfb[256 + tid];
  __syncthreads();
  int c = c0 + tid;
  if (tid < 125 && c < NC) {
    float acc = hb[c];
    const float* wrow = hw + (size_t)c * DD;
    for (int d = 0; d < DD; d += 4) {
      float4 w4 = *(const float4*)&wrow[d];
      acc += u0[d] * w4.x + u0[d + 1] * w4.y + u0[d + 2] * w4.z + u0[d + 3] * w4.w;
    }
    out[(size_t)b * NC + c] = acc;
  }
}

// ---------------------------------------------------------------------------
extern "C" void kernel_launch(void* const* d_in, const int* in_sizes, int n_in,
                              void* d_out, int out_size, void* d_ws, size_t ws_size,
                              hipStream_t stream) {
  const float* x       = (const float*)d_in[0];
  const float* patch_w = (const float*)d_in[1];
  const float* patch_b = (const float*)d_in[2];
  const float* cls     = (const float*)d_in[3];
  const float* pos     = (const float*)d_in[4];
  const float* in_proj = (const float*)d_in[5];
  const float* conv_w  = (const float*)d_in[6];
  const float* conv_b  = (const float*)d_in[7];
  const float* x_proj  = (const float*)d_in[8];
  const float* dt_w    = (const float*)d_in[9];
  const float* dt_b    = (const float*)d_in[10];
  const float* A_log   = (const float*)d_in[11];
  const float* D_ssm   = (const float*)d_in[12];
  const float* out_w   = (const float*)d_in[13];
  const float* norm_w  = (const float*)d_in[14];
  const float* norm_b  = (const float*)d_in[15];
  const float* normf_w = (const float*)d_in[16];
  const float* normf_b = (const float*)d_in[17];
  const float* head_w  = (const float*)d_in[18];
  const float* head_b  = (const float*)d_in[19];
  float* out = (float*)d_out;

  float* ws = (float*)d_ws;
  float* res = ws;  ws += (size_t)TT * DD;
  float* hid = ws;  ws += (size_t)TT * DD;   // out_proj out; Hend (w/ u) mid-layer
  float* u   = ws;  ws += (size_t)TT * DD;
  float* xzb = ws;  ws += (size_t)TT * 2 * DI;
  float* xcb = ws;  ws += (size_t)TT * DI;
  float* dbl = ws;  ws += (size_t)TT * 56;
  float* yb  = ws;  ws += (size_t)TT * DI;   // dt written by dtproj; y overwrites (same-thread RAW)
  float* crg = ws;  ws += (size_t)TT * DI;
  float* Aprod = crg;                        // 2.36M <= 2.42M
  float* Hend = hid;                         // spans hid+u (2.42M) — R10-proven

  k_init<<<(TT * DD + 255) / 256, 256, 0, stream>>>(cls, pos, res, hid);
  k_patch<<<dim3(49, 6), 256, 0, stream>>>(x, patch_w, patch_b, pos, hid);

  for (int layer = 0; layer < DEPTH; layer++) {
    k_addln<<<TT, 128, 0, stream>>>(res, hid, u, norm_w + layer * DD, norm_b + layer * DD);
    // in_proj: u (3152,384) @ Win^T (1536,384) -> xz (3152,1536)
    k_gemm_mfma<<<dim3(50, 24), 256, 0, stream>>>(
        u, DD, in_proj + (size_t)layer * 2 * DI * DD, DD, xzb, 2 * DI, TT, 2 * DI, DD);
    k_conv<<<(TT * (DI / 4) + 255) / 256, 256, 0, stream>>>(
        xzb, conv_w + layer * DI * 4, conv_b + layer * DI, xcb);
    // x_proj: xc (3152,768) @ Wx^T (56,768) -> dbl (3152,56)
    k_xproj<<<dim3(TT / 16), 256, 0, stream>>>(
        xcb, x_proj + (size_t)layer * 56 * DI, dbl);
    // dt: softplus(dbl[:, :24] @ Wdt^T + bdt) -> yb (as dt)
    k_dtproj<<<dim3(50, 12), 256, 0, stream>>>(
        dbl, dt_w + (size_t)layer * DI * DTR, dt_b + layer * DI, yb);
    // scan: lean pass1 -> lean pass2 (carry fused); y overwrites yb
    k_scan1<<<dim3(DI / 128, BB, NCHUNK), 256, 0, stream>>>(
        yb, xcb, dbl, A_log + (size_t)layer * DI * DSN, Aprod, Hend);
    k_scan2<<<dim3(DI / 128, BB, NCHUNK), 256, 0, stream>>>(
        yb, xcb, xzb, dbl, A_log + (size_t)layer * DI * DSN,
        D_ssm + layer * DI, Aprod, Hend, yb);
    // out_proj: y (3152,768) @ Wout^T (384,768) -> hid
    k_gemm_mfma<<<dim3(50, 6), 256, 0, stream>>>(
        yb, DI, out_w + (size_t)layer * DD * DI, DI, hid, DD, TT, DD, DI);
  }

  k_final<<<dim3(8, BB), 256, 0, stream>>>(res, hid, normf_w, normf_b, head_w, head_b, out);
}

// Round 12
// 2859.868 us; speedup vs baseline: 1.4090x; 1.2095x over previous
//
#include <hip/hip_runtime.h>
#include <hip/hip_bf16.h>
#include <math.h>

// Model dims
#define BB     16
#define LL     197
#define DD     384
#define DEPTH  24
#define DI     768
#define DSN    16
#define DTR    24
#define NC     1000
#define TT     (BB*LL)      // 3152 tokens
#define NPATCH 196
#define EPSV   1e-5f

// chunked scan config: 12 chunks of 17 tokens
#define NCHUNK 12
#define CH     17

typedef __attribute__((ext_vector_type(8))) short short8;
typedef __attribute__((ext_vector_type(4))) short short4v;
typedef __attribute__((ext_vector_type(4))) float f32x4;

__device__ __forceinline__ short f2bf(float f) {
  union { float f; unsigned u; } v; v.f = f;
  unsigned u = v.u + 0x7fffu + ((v.u >> 16) & 1u);
  return (short)(u >> 16);
}

// ---------------------------------------------------------------------------
// fp32 -> bf16 bulk convert (weights, once per call)
// ---------------------------------------------------------------------------
__global__ __launch_bounds__(256) void k_cvt(const float* __restrict__ src,
                                             short* __restrict__ dst, int n) {
  int i = (blockIdx.x * 256 + threadIdx.x) * 4;
  if (i + 3 < n) {
    float4 v = *(const float4*)&src[i];
    short4v o = {f2bf(v.x), f2bf(v.y), f2bf(v.z), f2bf(v.w)};
    *(short4v*)&dst[i] = o;
  } else {
    for (int j = 0; i + j < n && j < 4; j++) dst[i + j] = f2bf(src[i + j]);
  }
}

// ---------------------------------------------------------------------------
// init: zero res, write cls token row of hid
// ---------------------------------------------------------------------------
__global__ __launch_bounds__(256) void k_init(const float* __restrict__ cls,
                                              const float* __restrict__ pos,
                                              float* __restrict__ res,
                                              float* __restrict__ hid) {
  int i = blockIdx.x * 256 + threadIdx.x;
  if (i < TT * DD) res[i] = 0.f;
  if (i < BB * DD) {
    int b = i / DD, d = i % DD;
    hid[(size_t)(b * LL) * DD + d] = cls[d] + pos[d];
  }
}

// ---------------------------------------------------------------------------
// patch embed: bf16 MFMA GEMM with fused im2col (runs once; fp32 inputs)
// ---------------------------------------------------------------------------
__global__ __launch_bounds__(256) void k_patch(const float* __restrict__ x,
                                               const float* __restrict__ pw,
                                               const float* __restrict__ pb,
                                               const float* __restrict__ pos,
                                               float* __restrict__ hid) {
  __shared__ short sA[64 * 40];
  __shared__ short sB[64 * 40];
  const int tid = threadIdx.x;
  const int m0 = blockIdx.x * 64, n0 = blockIdx.y * 64;
  const int srow = tid >> 2;
  const int skq = (tid & 3) * 8;
  const int lane = tid & 63, w = tid >> 6;
  const int wm = (w >> 1) * 32, wn = (w & 1) * 32;
  const int fr = lane & 15;
  const int fk = (lane >> 4) * 8;
  f32x4 acc[2][2] = {};
  const int m = m0 + srow;
  const int b = m / NPATCH;
  const int p = m % NPATCH;
  const int ph = p / 14, pwi = p % 14;
  const float* Wrow = pw + (size_t)(n0 + srow) * 768 + skq;
  for (int k0 = 0; k0 < 768; k0 += 32) {
    int k = k0 + skq;
    int c = k >> 8, rr = (k >> 4) & 15, kw = k & 15;
    const float* xrow = &x[(size_t)(((b * 3 + c) * 224) + (ph * 16 + rr)) * 224 +
                           (pwi * 16 + kw)];
    float4 a0 = *(const float4*)&xrow[0];
    float4 a1 = *(const float4*)&xrow[4];
    float4 b0 = *(const float4*)&Wrow[k0];
    float4 b1 = *(const float4*)&Wrow[k0 + 4];
    short8 av = {f2bf(a0.x), f2bf(a0.y), f2bf(a0.z), f2bf(a0.w),
                 f2bf(a1.x), f2bf(a1.y), f2bf(a1.z), f2bf(a1.w)};
    short8 bv = {f2bf(b0.x), f2bf(b0.y), f2bf(b0.z), f2bf(b0.w),
                 f2bf(b1.x), f2bf(b1.y), f2bf(b1.z), f2bf(b1.w)};
    *(short8*)&sA[srow * 40 + skq] = av;
    *(short8*)&sB[srow * 40 + skq] = bv;
    __syncthreads();
    short8 af0 = *(const short8*)&sA[(wm + fr) * 40 + fk];
    short8 af1 = *(const short8*)&sA[(wm + 16 + fr) * 40 + fk];
    short8 bf0 = *(const short8*)&sB[(wn + fr) * 40 + fk];
    short8 bf1 = *(const short8*)&sB[(wn + 16 + fr) * 40 + fk];
    acc[0][0] = __builtin_amdgcn_mfma_f32_16x16x32_bf16(af0, bf0, acc[0][0], 0, 0, 0);
    acc[0][1] = __builtin_amdgcn_mfma_f32_16x16x32_bf16(af0, bf1, acc[0][1], 0, 0, 0);
    acc[1][0] = __builtin_amdgcn_mfma_f32_16x16x32_bf16(af1, bf0, acc[1][0], 0, 0, 0);
    acc[1][1] = __builtin_amdgcn_mfma_f32_16x16x32_bf16(af1, bf1, acc[1][1], 0, 0, 0);
    __syncthreads();
  }
#pragma unroll
  for (int i = 0; i < 2; i++)
#pragma unroll
    for (int j = 0; j < 2; j++)
#pragma unroll
      for (int q = 0; q < 4; q++) {
        int mm = m0 + wm + i * 16 + (lane >> 4) * 4 + q;
        int nn = n0 + wn + j * 16 + (lane & 15);
        int b2 = mm / NPATCH, pp = mm % NPATCH;
        int tok = b2 * LL + 1 + pp;
        hid[(size_t)tok * DD + nn] = acc[i][j][q] + pb[nn] + pos[(size_t)(1 + pp) * DD + nn];
      }
}

// ---------------------------------------------------------------------------
// bf16-in MFMA GEMM: C[M,N] = A[M,K] * W[N,K]^T, A and W already bf16.
// ---------------------------------------------------------------------------
__global__ __launch_bounds__(256) void k_gemm_bb(const short* __restrict__ A, int lda,
                                                 const short* __restrict__ W, int ldb,
                                                 float* __restrict__ C, int ldc,
                                                 int M, int N, int K) {
  __shared__ short sA[64 * 40];
  __shared__ short sB[64 * 40];
  const int tid = threadIdx.x;
  const int m0 = blockIdx.x * 64, n0 = blockIdx.y * 64;
  const int srow = tid >> 2;
  const int skq = (tid & 3) * 8;
  const int lane = tid & 63, w = tid >> 6;
  const int wm = (w >> 1) * 32, wn = (w & 1) * 32;
  const int fr = lane & 15;
  const int fk = (lane >> 4) * 8;
  f32x4 acc[2][2] = {};
  const int am = m0 + srow;
  const bool aok = am < M;
  const short* Arow = A + (size_t)am * lda + skq;
  const short* Wrow = W + (size_t)(n0 + srow) * ldb + skq;
  for (int k0 = 0; k0 < K; k0 += 32) {
    short8 av = {0, 0, 0, 0, 0, 0, 0, 0};
    if (aok) av = *(const short8*)&Arow[k0];
    short8 bv = *(const short8*)&Wrow[k0];
    *(short8*)&sA[srow * 40 + skq] = av;
    *(short8*)&sB[srow * 40 + skq] = bv;
    __syncthreads();
    short8 af0 = *(const short8*)&sA[(wm + fr) * 40 + fk];
    short8 af1 = *(const short8*)&sA[(wm + 16 + fr) * 40 + fk];
    short8 bf0 = *(const short8*)&sB[(wn + fr) * 40 + fk];
    short8 bf1 = *(const short8*)&sB[(wn + 16 + fr) * 40 + fk];
    acc[0][0] = __builtin_amdgcn_mfma_f32_16x16x32_bf16(af0, bf0, acc[0][0], 0, 0, 0);
    acc[0][1] = __builtin_amdgcn_mfma_f32_16x16x32_bf16(af0, bf1, acc[0][1], 0, 0, 0);
    acc[1][0] = __builtin_amdgcn_mfma_f32_16x16x32_bf16(af1, bf0, acc[1][0], 0, 0, 0);
    acc[1][1] = __builtin_amdgcn_mfma_f32_16x16x32_bf16(af1, bf1, acc[1][1], 0, 0, 0);
    __syncthreads();
  }
#pragma unroll
  for (int i = 0; i < 2; i++)
#pragma unroll
    for (int j = 0; j < 2; j++)
#pragma unroll
      for (int q = 0; q < 4; q++) {
        int mm = m0 + wm + i * 16 + (lane >> 4) * 4 + q;
        int nn = n0 + wn + j * 16 + (lane & 15);
        if (mm < M) C[(size_t)mm * ldc + nn] = acc[i][j][q];
      }
}

// ---------------------------------------------------------------------------
// dt projection: A = dbl fp32, W bf16 (pre-converted), K=24 padded to 32.
// softplus epilogue; dt -> C (ldc=DI)
// ---------------------------------------------------------------------------
__global__ __launch_bounds__(256) void k_dtproj(const float* __restrict__ A,
                                                const short* __restrict__ W,
                                                const float* __restrict__ bias,
                                                float* __restrict__ C) {
  __shared__ short sA[64 * 40];
  __shared__ short sB[64 * 40];
  const int tid = threadIdx.x;
  const int m0 = blockIdx.x * 64, n0 = blockIdx.y * 64;
  const int srow = tid >> 2;
  const int skq = (tid & 3) * 8;
  const int lane = tid & 63, w = tid >> 6;
  const int wm = (w >> 1) * 32, wn = (w & 1) * 32;
  const int fr = lane & 15;
  const int fk = (lane >> 4) * 8;
  f32x4 acc[2][2] = {};
  const int am = m0 + srow;
  short8 av = {0, 0, 0, 0, 0, 0, 0, 0}, bv = {0, 0, 0, 0, 0, 0, 0, 0};
  if (skq < 24) {
    if (am < TT) {
      float4 a0 = *(const float4*)&A[(size_t)am * 56 + skq];
      float4 a1 = *(const float4*)&A[(size_t)am * 56 + skq + 4];
      av = short8{f2bf(a0.x), f2bf(a0.y), f2bf(a0.z), f2bf(a0.w),
                  f2bf(a1.x), f2bf(a1.y), f2bf(a1.z), f2bf(a1.w)};
    }
    bv = *(const short8*)&W[(size_t)(n0 + srow) * 24 + skq];
  }
  *(short8*)&sA[srow * 40 + skq] = av;
  *(short8*)&sB[srow * 40 + skq] = bv;
  __syncthreads();
  short8 af0 = *(const short8*)&sA[(wm + fr) * 40 + fk];
  short8 af1 = *(const short8*)&sA[(wm + 16 + fr) * 40 + fk];
  short8 bf0 = *(const short8*)&sB[(wn + fr) * 40 + fk];
  short8 bf1 = *(const short8*)&sB[(wn + 16 + fr) * 40 + fk];
  acc[0][0] = __builtin_amdgcn_mfma_f32_16x16x32_bf16(af0, bf0, acc[0][0], 0, 0, 0);
  acc[0][1] = __builtin_amdgcn_mfma_f32_16x16x32_bf16(af0, bf1, acc[0][1], 0, 0, 0);
  acc[1][0] = __builtin_amdgcn_mfma_f32_16x16x32_bf16(af1, bf0, acc[1][0], 0, 0, 0);
  acc[1][1] = __builtin_amdgcn_mfma_f32_16x16x32_bf16(af1, bf1, acc[1][1], 0, 0, 0);
#pragma unroll
  for (int i = 0; i < 2; i++)
#pragma unroll
    for (int j = 0; j < 2; j++)
#pragma unroll
      for (int q = 0; q < 4; q++) {
        int mm = m0 + wm + i * 16 + (lane >> 4) * 4 + q;
        int nn = n0 + wn + j * 16 + (lane & 15);
        if (mm < TT) {
          float v = acc[i][j][q] + bias[nn];
          v = (v > 20.f) ? v : log1pf(__expf(v));
          C[(size_t)mm * DI + nn] = v;
        }
      }
}

// ---------------------------------------------------------------------------
// x_proj: bf16-in, BM=16, N=56 padded to 64, K=768. A=xc_bf16, W bf16.
// ---------------------------------------------------------------------------
__global__ __launch_bounds__(256) void k_xproj(const short* __restrict__ A,
                                               const short* __restrict__ W,
                                               float* __restrict__ C) {
  __shared__ short sA[16 * 40];
  __shared__ short sB[64 * 40];
  const int tid = threadIdx.x;
  const int m0 = blockIdx.x * 16;
  const int lane = tid & 63, w = tid >> 6;
  const int wn = w * 16;
  const int fr = lane & 15;
  const int fk = (lane >> 4) * 8;
  const int srow = tid >> 2;
  const int skq = (tid & 3) * 8;
  f32x4 acc = {};
  for (int k0 = 0; k0 < DI; k0 += 32) {
    if (tid < 64) {
      *(short8*)&sA[srow * 40 + skq] =
          *(const short8*)&A[(size_t)(m0 + srow) * DI + k0 + skq];
    }
    short8 bv = {0, 0, 0, 0, 0, 0, 0, 0};
    if (srow < 56) bv = *(const short8*)&W[(size_t)srow * DI + k0 + skq];
    *(short8*)&sB[srow * 40 + skq] = bv;
    __syncthreads();
    short8 af = *(const short8*)&sA[fr * 40 + fk];
    short8 bf = *(const short8*)&sB[(wn + fr) * 40 + fk];
    acc = __builtin_amdgcn_mfma_f32_16x16x32_bf16(af, bf, acc, 0, 0, 0);
    __syncthreads();
  }
#pragma unroll
  for (int q = 0; q < 4; q++) {
    int mm = m0 + (lane >> 4) * 4 + q;
    int nn = wn + (lane & 15);
    if (nn < 56) C[(size_t)mm * 56 + nn] = acc[q];
  }
}

// ---------------------------------------------------------------------------
// res += hid; u = LN(res)*nw+nb, u written as bf16
// ---------------------------------------------------------------------------
__global__ __launch_bounds__(128) void k_addln(float* __restrict__ res,
                                               const float* __restrict__ hid,
                                               short* __restrict__ u,
                                               const float* __restrict__ nw,
                                               const float* __restrict__ nb) {
  const int t = blockIdx.x;
  const int tid = threadIdx.x;
  float r[3];
  float s = 0.f, sq = 0.f;
#pragma unroll
  for (int j = 0; j < 3; j++) {
    int d = tid + j * 128;
    float v = res[(size_t)t * DD + d] + hid[(size_t)t * DD + d];
    res[(size_t)t * DD + d] = v;
    r[j] = v;
    s += v; sq += v * v;
  }
#pragma unroll
  for (int o = 32; o > 0; o >>= 1) { s += __shfl_xor(s, o); sq += __shfl_xor(sq, o); }
  __shared__ float ls[2], lq[2];
  int w = tid >> 6;
  if ((tid & 63) == 0) { ls[w] = s; lq[w] = sq; }
  __syncthreads();
  float st = ls[0] + ls[1], qt = lq[0] + lq[1];
  float mu = st * (1.f / 384.f);
  float var = qt * (1.f / 384.f) - mu * mu;
  float rs = rsqrtf(var + EPSV);
#pragma unroll
  for (int j = 0; j < 3; j++) {
    int d = tid + j * 128;
    u[(size_t)t * DD + d] = f2bf((r[j] - mu) * rs * nw[d] + nb[d]);
  }
}

// ---------------------------------------------------------------------------
// causal depthwise conv + bias + SiLU — float4; writes xc fp32 and xc bf16
// ---------------------------------------------------------------------------
__global__ __launch_bounds__(256) void k_conv(const float* __restrict__ xz,
                                              const float* __restrict__ wc,
                                              const float* __restrict__ bc,
                                              float* __restrict__ xc,
                                              short* __restrict__ xcbf) {
  int i = blockIdx.x * 256 + threadIdx.x;   // over TT*DI/4
  if (i >= TT * (DI / 4)) return;
  int eg = i % (DI / 4);
  int t = i / (DI / 4);
  int e = eg * 4;
  int b = t / LL, l = t % LL;
  const float* base = xz + (size_t)(b * LL) * (2 * DI) + e;
  float4 w0 = *(const float4*)&wc[(e + 0) * 4];
  float4 w1 = *(const float4*)&wc[(e + 1) * 4];
  float4 w2 = *(const float4*)&wc[(e + 2) * 4];
  float4 w3 = *(const float4*)&wc[(e + 3) * 4];
  float4 acc = *(const float4*)&bc[e];
  if (l >= 3) {
    float4 xv = *(const float4*)&base[(size_t)(l - 3) * (2 * DI)];
    acc.x += xv.x * w0.x; acc.y += xv.y * w1.x; acc.z += xv.z * w2.x; acc.w += xv.w * w3.x;
  }
  if (l >= 2) {
    float4 xv = *(const float4*)&base[(size_t)(l - 2) * (2 * DI)];
    acc.x += xv.x * w0.y; acc.y += xv.y * w1.y; acc.z += xv.z * w2.y; acc.w += xv.w * w3.y;
  }
  if (l >= 1) {
    float4 xv = *(const float4*)&base[(size_t)(l - 1) * (2 * DI)];
    acc.x += xv.x * w0.z; acc.y += xv.y * w1.z; acc.z += xv.z * w2.z; acc.w += xv.w * w3.z;
  }
  {
    float4 xv = *(const float4*)&base[(size_t)l * (2 * DI)];
    acc.x += xv.x * w0.w; acc.y += xv.y * w1.w; acc.z += xv.z * w2.w; acc.w += xv.w * w3.w;
  }
  acc.x = acc.x / (1.f + __expf(-acc.x));
  acc.y = acc.y / (1.f + __expf(-acc.y));
  acc.z = acc.z / (1.f + __expf(-acc.z));
  acc.w = acc.w / (1.f + __expf(-acc.w));
  *(float4*)&xc[(size_t)t * DI + e] = acc;
  short4v ov = {f2bf(acc.x), f2bf(acc.y), f2bf(acc.z), f2bf(acc.w)};
  *(short4v*)&xcbf[(size_t)t * DI + e] = ov;
}

// ---------------------------------------------------------------------------
// lean scan pass 1: register h[8], thread = (e, n-half).
// ---------------------------------------------------------------------------
__global__ __launch_bounds__(256) void k_scan1(const float* __restrict__ dt,
                                               const float* __restrict__ xc,
                                               const float* __restrict__ dbl,
                                               const float* __restrict__ Alog,
                                               float* __restrict__ Aprod,
                                               float* __restrict__ Hend) {
  const int tid = threadIdx.x;
  const int e = blockIdx.x * 128 + (tid >> 1);
  const int nh = tid & 1;
  const int b = blockIdx.y;
  const int c = blockIdx.z;
  float4 al0 = *(const float4*)&Alog[(size_t)e * DSN + nh * 8];
  float4 al1 = *(const float4*)&Alog[(size_t)e * DSN + nh * 8 + 4];
  float negA[8] = {-__expf(al0.x), -__expf(al0.y), -__expf(al0.z), -__expf(al0.w),
                   -__expf(al1.x), -__expf(al1.y), -__expf(al1.z), -__expf(al1.w)};
  float h[8] = {};
  float asum = 0.f;
  const int l0 = c * CH;
  const int l1 = (l0 + CH < LL) ? (l0 + CH) : LL;
  const size_t tbase = (size_t)b * LL;
  for (int l = l0; l < l1; l++) {
    size_t t = tbase + l;
    float dtv = dt[t * DI + e];
    float xcv = xc[t * DI + e];
    float4 B0 = *(const float4*)&dbl[t * 56 + DTR + nh * 8];
    float4 B1 = *(const float4*)&dbl[t * 56 + DTR + nh * 8 + 4];
    float dx = dtv * xcv;
    float Bv[8] = {B0.x, B0.y, B0.z, B0.w, B1.x, B1.y, B1.z, B1.w};
#pragma unroll
    for (int j = 0; j < 8; j++)
      h[j] = __expf(dtv * negA[j]) * h[j] + dx * Bv[j];
    asum += dtv;
  }
  size_t ci = (((size_t)c * BB + b) * DI + e) * DSN + nh * 8;
  *(float4*)&Aprod[ci] = float4{__expf(asum * negA[0]), __expf(asum * negA[1]),
                                __expf(asum * negA[2]), __expf(asum * negA[3])};
  *(float4*)&Aprod[ci + 4] = float4{__expf(asum * negA[4]), __expf(asum * negA[5]),
                                    __expf(asum * negA[6]), __expf(asum * negA[7])};
  *(float4*)&Hend[ci] = float4{h[0], h[1], h[2], h[3]};
  *(float4*)&Hend[ci + 4] = float4{h[4], h[5], h[6], h[7]};
}

// ---------------------------------------------------------------------------
// lean scan pass 2: carry fold + recurrence + gating; y written as bf16.
// ---------------------------------------------------------------------------
__global__ __launch_bounds__(256) void k_scan2(const float* __restrict__ dt,
                                               const float* __restrict__ xc,
                                               const float* __restrict__ xz,
                                               const float* __restrict__ dbl,
                                               const float* __restrict__ Alog,
                                               const float* __restrict__ Dp,
                                               const float* __restrict__ Aprod,
                                               const float* __restrict__ Hend,
                                               short* __restrict__ ybf) {
  const int tid = threadIdx.x;
  const int e = blockIdx.x * 128 + (tid >> 1);
  const int nh = tid & 1;
  const int b = blockIdx.y;
  const int c = blockIdx.z;
  float4 al0 = *(const float4*)&Alog[(size_t)e * DSN + nh * 8];
  float4 al1 = *(const float4*)&Alog[(size_t)e * DSN + nh * 8 + 4];
  float negA[8] = {-__expf(al0.x), -__expf(al0.y), -__expf(al0.z), -__expf(al0.w),
                   -__expf(al1.x), -__expf(al1.y), -__expf(al1.z), -__expf(al1.w)};
  const float dpv = Dp[e];
  float h[8] = {};
  const size_t cstride = (size_t)BB * DI * DSN;
  const size_t cbase = (((size_t)b * DI + e) * DSN) + nh * 8;
  for (int cp = 0; cp < c; cp++) {
    size_t ci = (size_t)cp * cstride + cbase;
    float4 a0 = *(const float4*)&Aprod[ci];
    float4 a1 = *(const float4*)&Aprod[ci + 4];
    float4 e0 = *(const float4*)&Hend[ci];
    float4 e1 = *(const float4*)&Hend[ci + 4];
    h[0] = a0.x * h[0] + e0.x; h[1] = a0.y * h[1] + e0.y;
    h[2] = a0.z * h[2] + e0.z; h[3] = a0.w * h[3] + e0.w;
    h[4] = a1.x * h[4] + e1.x; h[5] = a1.y * h[5] + e1.y;
    h[6] = a1.z * h[6] + e1.z; h[7] = a1.w * h[7] + e1.w;
  }
  const int l0 = c * CH;
  const int l1 = (l0 + CH < LL) ? (l0 + CH) : LL;
  const size_t tbase = (size_t)b * LL;
  for (int l = l0; l < l1; l++) {
    size_t t = tbase + l;
    float dtv = dt[t * DI + e];
    float xcv = xc[t * DI + e];
    float zv = xz[t * (2 * DI) + DI + e];
    float4 B0 = *(const float4*)&dbl[t * 56 + DTR + nh * 8];
    float4 B1 = *(const float4*)&dbl[t * 56 + DTR + nh * 8 + 4];
    float4 C0 = *(const float4*)&dbl[t * 56 + DTR + DSN + nh * 8];
    float4 C1 = *(const float4*)&dbl[t * 56 + DTR + DSN + nh * 8 + 4];
    float dx = dtv * xcv;
    float Bv[8] = {B0.x, B0.y, B0.z, B0.w, B1.x, B1.y, B1.z, B1.w};
    float Cv[8] = {C0.x, C0.y, C0.z, C0.w, C1.x, C1.y, C1.z, C1.w};
    float acc = 0.f;
#pragma unroll
    for (int j = 0; j < 8; j++) {
      h[j] = __expf(dtv * negA[j]) * h[j] + dx * Bv[j];
      acc += h[j] * Cv[j];
    }
    acc += __shfl_xor(acc, 1);
    if (nh == 0) {
      float sz = zv * (1.f / (1.f + __expf(-zv)));
      ybf[t * DI + e] = f2bf((acc + xcv * dpv) * sz);
    }
  }
}

// ---------------------------------------------------------------------------
// final: LN(res[b,0] + hid[b,0]) -> head. grid (8, BB).
// ---------------------------------------------------------------------------
__global__ __launch_bounds__(256) void k_final(const float* __restrict__ res,
                                               const float* __restrict__ hid,
                                               const float* __restrict__ nfw,
                                               const float* __restrict__ nfb,
                                               const float* __restrict__ hw,
                                               const float* __restrict__ hb,
                                               float* __restrict__ out) {
  const int b = blockIdx.y;
  const int c0 = blockIdx.x * 125;
  const int tid = threadIdx.x;
  __shared__ float u0[DD];
  __shared__ float ls[4], lq[4];
  const size_t t0 = (size_t)b * LL * DD;
  float v0 = res[t0 + tid] + hid[t0 + tid];
  float v1 = (tid < 128) ? (res[t0 + 256 + tid] + hid[t0 + 256 + tid]) : 0.f;
  float s = v0 + v1, sq = v0 * v0 + v1 * v1;
#pragma unroll
  for (int o = 32; o > 0; o >>= 1) { s += __shfl_xor(s, o); sq += __shfl_xor(sq, o); }
  if ((tid & 63) == 0) { ls[tid >> 6] = s; lq[tid >> 6] = sq; }
  __syncthreads();
  float st = ls[0] + ls[1] + ls[2] + ls[3];
  float qt = lq[0] + lq[1] + lq[2] + lq[3];
  float mu = st * (1.f / 384.f);
  float var = qt * (1.f / 384.f) - mu * mu;
  float rs = rsqrtf(var + EPSV);
  u0[tid] = (v0 - mu) * rs * nfw[tid] + nfb[tid];
  if (tid < 128) u0[256 + tid] = (v1 - mu) * rs * nfw[256 + tid] + nfb[256 + tid];
  __syncthreads();
  int c = c0 + tid;
  if (tid < 125 && c < NC) {
    float acc = hb[c];
    const float* wrow = hw + (size_t)c * DD;
    for (int d = 0; d < DD; d += 4) {
      float4 w4 = *(const float4*)&wrow[d];
      acc += u0[d] * w4.x + u0[d + 1] * w4.y + u0[d + 2] * w4.z + u0[d + 3] * w4.w;
    }
    out[(size_t)b * NC + c] = acc;
  }
}

// ---------------------------------------------------------------------------
extern "C" void kernel_launch(void* const* d_in, const int* in_sizes, int n_in,
                              void* d_out, int out_size, void* d_ws, size_t ws_size,
                              hipStream_t stream) {
  const float* x       = (const float*)d_in[0];
  const float* patch_w = (const float*)d_in[1];
  const float* patch_b = (const float*)d_in[2];
  const float* cls     = (const float*)d_in[3];
  const float* pos     = (const float*)d_in[4];
  const float* in_proj = (const float*)d_in[5];
  const float* conv_w  = (const float*)d_in[6];
  const float* conv_b  = (const float*)d_in[7];
  const float* x_proj  = (const float*)d_in[8];
  const float* dt_w    = (const float*)d_in[9];
  const float* dt_b    = (const float*)d_in[10];
  const float* A_log   = (const float*)d_in[11];
  const float* D_ssm   = (const float*)d_in[12];
  const float* out_w   = (const float*)d_in[13];
  const float* norm_w  = (const float*)d_in[14];
  const float* norm_b  = (const float*)d_in[15];
  const float* normf_w = (const float*)d_in[16];
  const float* normf_b = (const float*)d_in[17];
  const float* head_w  = (const float*)d_in[18];
  const float* head_b  = (const float*)d_in[19];
  float* out = (float*)d_out;

  float* ws = (float*)d_ws;
  float* res = ws;  ws += (size_t)TT * DD;
  float* hid = ws;  ws += (size_t)TT * DD;    // Hend spans hid+u (R10/R11-proven)
  float* u_r = ws;  ws += (size_t)TT * DD;    // holds u as bf16 (half used)
  float* xzb = ws;  ws += (size_t)TT * 2 * DI;
  float* xcb = ws;  ws += (size_t)TT * DI;
  float* dbl = ws;  ws += (size_t)TT * 56;
  float* dtb = ws;  ws += (size_t)TT * DI;    // dt fp32 (no aliasing now)
  float* crg = ws;  ws += (size_t)TT * DI;    // Aprod
  float* xcbf_r = ws; ws += (size_t)TT * DI / 2;  // xc bf16
  float* ybf_r  = ws; ws += (size_t)TT * DI / 2;  // y bf16
  // bf16 weights (converted once per call); ws_size = 256 MiB, total ~123 MB
  short* winbf  = (short*)ws; ws += (size_t)DEPTH * 2 * DI * DD / 2;
  short* woutbf = (short*)ws; ws += (size_t)DEPTH * DD * DI / 2;
  short* wxbf   = (short*)ws; ws += (size_t)DEPTH * 56 * DI / 2;
  short* wdtbf  = (short*)ws; ws += (size_t)DEPTH * DI * DTR / 2;

  short* u    = (short*)u_r;
  short* xcbf = (short*)xcbf_r;
  short* ybf  = (short*)ybf_r;
  float* Aprod = crg;
  float* Hend  = hid;   // spans hid+u (2.42M floats) — R10/R11-proven

  // one-time (per call) weight conversions
  {
    int n1 = DEPTH * 2 * DI * DD;
    k_cvt<<<(n1 / 4 + 255) / 256, 256, 0, stream>>>(in_proj, winbf, n1);
    int n2 = DEPTH * DD * DI;
    k_cvt<<<(n2 / 4 + 255) / 256, 256, 0, stream>>>(out_w, woutbf, n2);
    int n3 = DEPTH * 56 * DI;
    k_cvt<<<(n3 / 4 + 255) / 256, 256, 0, stream>>>(x_proj, wxbf, n3);
    int n4 = DEPTH * DI * DTR;
    k_cvt<<<(n4 / 4 + 255) / 256, 256, 0, stream>>>(dt_w, wdtbf, n4);
  }

  k_init<<<(TT * DD + 255) / 256, 256, 0, stream>>>(cls, pos, res, hid);
  k_patch<<<dim3(49, 6), 256, 0, stream>>>(x, patch_w, patch_b, pos, hid);

  for (int layer = 0; layer < DEPTH; layer++) {
    k_addln<<<TT, 128, 0, stream>>>(res, hid, u, norm_w + layer * DD, norm_b + layer * DD);
    // in_proj: u_bf16 (3152,384) @ Win_bf16^T (1536,384) -> xz fp32
    k_gemm_bb<<<dim3(50, 24), 256, 0, stream>>>(
        u, DD, winbf + (size_t)layer * 2 * DI * DD, DD, xzb, 2 * DI, TT, 2 * DI, DD);
    k_conv<<<(TT * (DI / 4) + 255) / 256, 256, 0, stream>>>(
        xzb, conv_w + layer * DI * 4, conv_b + layer * DI, xcb, xcbf);
    // x_proj: xc_bf16 @ Wx_bf16^T -> dbl fp32
    k_xproj<<<dim3(TT / 16), 256, 0, stream>>>(
        xcbf, wxbf + (size_t)layer * 56 * DI, dbl);
    // dt: softplus(dbl[:, :24] @ Wdt^T + bdt) -> dtb fp32
    k_dtproj<<<dim3(50, 12), 256, 0, stream>>>(
        dbl, wdtbf + (size_t)layer * DI * DTR, dt_b + layer * DI, dtb);
    // scan: lean pass1 -> lean pass2 (carry fused); y -> ybf (bf16)
    k_scan1<<<dim3(DI / 128, BB, NCHUNK), 256, 0, stream>>>(
        dtb, xcb, dbl, A_log + (size_t)layer * DI * DSN, Aprod, Hend);
    k_scan2<<<dim3(DI / 128, BB, NCHUNK), 256, 0, stream>>>(
        dtb, xcb, xzb, dbl, A_log + (size_t)layer * DI * DSN,
        D_ssm + layer * DI, Aprod, Hend, ybf);
    // out_proj: y_bf16 (3152,768) @ Wout_bf16^T (384,768) -> hid fp32
    k_gemm_bb<<<dim3(50, 6), 256, 0, stream>>>(
        ybf, DI, woutbf + (size_t)layer * DD * DI, DI, hid, DD, TT, DD, DI);
  }

  k_final<<<dim3(8, BB), 256, 0, stream>>>(res, hid, normf_w, normf_b, head_w, head_b, out);
}